// Round 11
// baseline (1288.258 us; speedup 1.0000x reference)
//
#include <hip/hip_runtime.h>

#define BS 16
#define SEQ 1024
#define EMB 128
#define NHEAD 4
#define LN_EPS 1e-5f

typedef __attribute__((ext_vector_type(8))) short bf16x8;
typedef __attribute__((ext_vector_type(8))) _Float16 f16x8;
typedef __attribute__((ext_vector_type(4))) float f32x4;
typedef __attribute__((ext_vector_type(4))) unsigned short u16x4;
typedef __attribute__((ext_vector_type(4))) unsigned int u32x4;

__device__ __forceinline__ unsigned short f2b(float f) {
  union { float f; unsigned u; } v; v.f = f;
  unsigned r = v.u + 0x7fff + ((v.u >> 16) & 1);
  return (unsigned short)(r >> 16);
}
__device__ __forceinline__ unsigned short f2h(float f) {
  union { _Float16 h; unsigned short u; } v; v.h = (_Float16)f; return v.u;
}
// split x into hi+lo bf16 (3-term Markidis precision: rel err ~2^-17)
__device__ __forceinline__ void split2(float x, unsigned short& hi, unsigned short& lo) {
  unsigned short h = f2b(x);
  float hf = __uint_as_float((unsigned)h << 16);
  hi = h; lo = f2b(x - hf);
}
__device__ __forceinline__ float rsqrt_acc(float v) {
  float r = rsqrtf(v);
  return r * (1.5f - 0.5f * v * r * r);   // one Newton step -> ~f32-exact
}

// ---------------- weight prep: fragment-ordered 2-plane bf16 ----------------
__global__ void k_prep_fragT(const float* __restrict__ in, unsigned short* __restrict__ out,
                             size_t PL, int L, int Kin, int Nin, int N, int K) {
  int idx = blockIdx.x * 256 + threadIdx.x;
  int nblk = (N >> 4) * (K >> 5);
  int total = L * N * K;
  if (idx >= total) return;
  int e = idx & 7;
  int lane = (idx >> 3) & 63;
  int blk = (idx >> 9) % nblk;
  int l = idx / (512 * nblk);
  int nb = blk % (N >> 4), kc = blk / (N >> 4);
  int n = nb * 16 + (lane & 15);
  int k = kc * 32 + (lane >> 4) * 8 + e;
  float v = (k < Kin && n < Nin) ? in[(size_t)l * Kin * Nin + (size_t)k * Nin + n] : 0.f;
  unsigned short hi, lo; split2(v, hi, lo);
  out[idx] = hi; out[PL + idx] = lo;
}

// qvW frag: N=512, K=128; n<256 q side (h=n>>6,d=n&63, d63 zero), else v side
__global__ void k_prep_qvfrag(const float* __restrict__ qW, const float* __restrict__ vW,
                              unsigned short* __restrict__ out, size_t PL) {
  int idx = blockIdx.x * 256 + threadIdx.x;
  int total = 11 * 512 * 128;
  if (idx >= total) return;
  int e = idx & 7;
  int lane = (idx >> 3) & 63;
  int blk = (idx >> 9) & 127;       // kc*32 + nb
  int l = idx >> 16;
  int nb = blk & 31, kc = blk >> 5;
  int n = nb * 16 + (lane & 15);
  int k = kc * 32 + (lane >> 4) * 8 + e;
  float v = 0.f;
  if (n < 256) {
    int hh = n >> 6, d = n & 63;
    if (d < 63 && k >= 64 && k < 127) v = qW[(size_t)l * 63 * 252 + (size_t)(k - 64) * 252 + hh * 63 + d];
  } else {
    int n2 = n - 256, hh = n2 >> 6, d = n2 & 63;
    if (d < 63 && k < 63) v = vW[(size_t)l * 63 * 252 + (size_t)k * 252 + hh * 63 + d];
  }
  unsigned short hi, lo; split2(v, hi, lo);
  out[idx] = hi; out[PL + idx] = lo;
}

// last-layer qkv frag: N=1536, K=128
__global__ void k_prep_lastfrag(const float* __restrict__ qW, const float* __restrict__ kW,
                                const float* __restrict__ vW,
                                unsigned short* __restrict__ out, size_t PL) {
  int idx = blockIdx.x * 256 + threadIdx.x;
  int total = 1536 * 128;
  if (idx >= total) return;
  int e = idx & 7;
  int lane = (idx >> 3) & 63;
  int blk = idx >> 9;               // kc*96 + nb
  int nb = blk % 96, kc = blk / 96;
  int n = nb * 16 + (lane & 15);
  int k = kc * 32 + (lane >> 4) * 8 + e;
  int tsel = n >> 9, n2 = n & 511;
  const float* W = tsel == 0 ? qW : (tsel == 1 ? kW : vW);
  float v = W[(size_t)k * 512 + n2];
  unsigned short hi, lo; split2(v, hi, lo);
  out[idx] = hi; out[PL + idx] = lo;
}

// ---------------- combine + read_in ----------------
__global__ void k_combine_readin(const float* __restrict__ xs, const float* __restrict__ ys,
                                 const float* __restrict__ W, const float* __restrict__ bias,
                                 float* __restrict__ H, unsigned short* __restrict__ Hbf, size_t hbPl,
                                 unsigned short* __restrict__ Hh) {
  int blk = blockIdx.x;            // b*1024 + t
  int b = blk >> 10, t = blk & 1023, p = t >> 1;
  __shared__ float zs[64];
  int tid = threadIdx.x;           // 128
  if (tid < 64) {
    float v;
    if (tid < 63) v = xs[((size_t)b * 512 + p) * 63 + tid];
    else v = (t & 1) ? ys[(size_t)b * 512 + p] : 0.f;
    zs[tid] = v;
  }
  __syncthreads();
  float acc = bias[tid];
  #pragma unroll 8
  for (int d = 0; d < 64; ++d) acc += zs[d] * W[d * 128 + tid];
  size_t o = (size_t)blk * 128 + tid;
  H[o] = acc;
  unsigned short hi, lo; split2(acc, hi, lo);
  Hbf[o] = hi; Hbf[hbPl + o] = lo;
  if (tid < 64) Hh[(size_t)blk * 64 + tid] = f2h(acc);  // fp16 K image (dims 0..63)
}

// ---------------- split-precision MFMA GEMM: A LDS-staged, B fragment-ordered ----------------
// MODE 0: mid frag-ordered packed u32; MODE 2: last qkv frag fp16; MODE 3: qv frag fp16
template<int MODE, bool RELU>
__global__ __launch_bounds__(256) void k_gemm(
    const unsigned short* __restrict__ A, size_t aPl,
    const unsigned short* __restrict__ BT, size_t bPl, const float* __restrict__ bias,
    int N,
    unsigned short* __restrict__ out0,
    unsigned short* __restrict__ out1,
    unsigned short* __restrict__ out2) {
  extern __shared__ unsigned short lds[];   // A 2 planes [64][136] = 34816 B; tile reuse
  int tid = threadIdx.x;
  int wid = tid >> 6, lane = tid & 63;
  int lr = lane & 15, lg = lane >> 4;
  int row0g = blockIdx.x * 64;
  int n0 = blockIdx.y * 64;
  unsigned short* Ah = lds;
  unsigned short* Al = Ah + 64 * 136;
  {
    const unsigned short* gA = A + (size_t)row0g * 128;
    const unsigned short* srcs[2] = { gA, gA + aPl };
    unsigned short* dsts[2] = { Ah, Al };
    #pragma unroll
    for (int p = 0; p < 2; ++p)
      #pragma unroll
      for (int it = 0; it < 4; ++it) {
        int e = it * 2048 + tid * 8;
        bf16x8 v = *reinterpret_cast<const bf16x8*>(srcs[p] + e);
        *reinterpret_cast<bf16x8*>(dsts[p] + (e >> 7) * 136 + (e & 127)) = v;
      }
  }
  __syncthreads();
  bf16x8 afh[4], afl[4];
  #pragma unroll
  for (int kf = 0; kf < 4; ++kf) {
    int o = (wid * 16 + lr) * 136 + kf * 32 + lg * 8;
    afh[kf] = *reinterpret_cast<const bf16x8*>(Ah + o);
    afl[kf] = *reinterpret_cast<const bf16x8*>(Al + o);
  }
  f32x4 acc[4] = {};
  int nhw = N >> 4;
  #pragma unroll
  for (int nf = 0; nf < 4; ++nf) {
    #pragma unroll
    for (int kf = 0; kf < 4; ++kf) {
      size_t bo = ((size_t)kf * nhw + (n0 >> 4) + nf) * 512 + lane * 8;
      bf16x8 bh = *reinterpret_cast<const bf16x8*>(BT + bo);
      bf16x8 bl = *reinterpret_cast<const bf16x8*>(BT + bPl + bo);
      acc[nf] = __builtin_amdgcn_mfma_f32_16x16x32_bf16(afh[kf], bh, acc[nf], 0, 0, 0);
      acc[nf] = __builtin_amdgcn_mfma_f32_16x16x32_bf16(afl[kf], bh, acc[nf], 0, 0, 0);
      acc[nf] = __builtin_amdgcn_mfma_f32_16x16x32_bf16(afh[kf], bl, acc[nf], 0, 0, 0);
    }
  }
  __syncthreads();   // done with staged A; reuse lds for the output tile
  #pragma unroll
  for (int nf = 0; nf < 4; ++nf) {
    int c = n0 + nf * 16 + lr;
    float bv = bias ? bias[c] : 0.f;
    #pragma unroll
    for (int r = 0; r < 4; ++r) {
      float v = acc[nf][r] + bv;
      if (RELU) v = fmaxf(v, 0.f);
      int rL = wid * 16 + lg * 4 + r, cL = nf * 16 + lr;
      if (MODE == 0) {
        unsigned short hi, lo; split2(v, hi, lo);
        ((unsigned int(*)[65])lds)[rL][cL] = (unsigned)hi | ((unsigned)lo << 16);
      } else {
        ((unsigned short(*)[66])lds)[rL][cL] = f2h(v);
      }
    }
  }
  __syncthreads();
  int u = tid * 2;
  int lane2 = u >> 3, e0 = u & 7;
  if (MODE == 0) {
    unsigned int* o32 = (unsigned int*)out0;
    unsigned int (*tile)[65] = (unsigned int(*)[65])lds;
    int rb0 = row0g >> 4, kc0 = n0 >> 5;
    #pragma unroll
    for (int fb = 0; fb < 8; ++fb) {
      int rbl = fb >> 1, kcl = fb & 1;
      int row_l = rbl * 16 + (lane2 & 15);
      int c_l = kcl * 32 + ((lane2 >> 4) << 3) + e0;
      size_t dst = ((((size_t)rb0 + rbl) * 16 + kc0 + kcl) * 64 + lane2) * 8 + e0;
      o32[dst] = tile[row_l][c_l];
      o32[dst + 1] = tile[row_l][c_l + 1];
    }
  } else if (MODE == 2) {
    unsigned short (*t16)[66] = (unsigned short(*)[66])lds;
    int b = row0g >> 10, t0 = row0g & 1023;
    int tsel = n0 >> 9, c2b = n0 & 511, hh = c2b >> 7, dbase = c2b & 127;
    size_t bh = (size_t)b * NHEAD + hh;
    if (tsel < 2) {
      unsigned short* base = tsel ? out1 : out0;
      int tb0 = t0 >> 4, kc0 = dbase >> 5;
      #pragma unroll
      for (int fb = 0; fb < 8; ++fb) {
        int tbl = fb >> 1, kcl = fb & 1;
        int t_l = tbl * 16 + (lane2 & 15);
        int c_l = kcl * 32 + ((lane2 >> 4) << 3) + e0;
        size_t dst = ((bh * 64 + tb0 + tbl) * 4 + kc0 + kcl) * 512 + lane2 * 8 + e0;
        base[dst] = t16[t_l][c_l];
        base[dst + 1] = t16[t_l][c_l + 1];
      }
    } else {
      int db0 = dbase >> 4, jc0 = t0 >> 5;
      #pragma unroll
      for (int fb = 0; fb < 8; ++fb) {
        int dbl = fb >> 1, jcl = fb & 1;
        int c_l = dbl * 16 + (lane2 & 15);
        int t_l = jcl * 32 + ((lane2 >> 4) << 3) + e0;
        size_t dst = ((bh * 8 + db0 + dbl) * 32 + jc0 + jcl) * 512 + lane2 * 8 + e0;
        out2[dst] = t16[t_l][c_l];
        out2[dst + 1] = t16[t_l + 1][c_l];
      }
    }
  } else {  // MODE 3
    unsigned short (*t16)[66] = (unsigned short(*)[66])lds;
    int b = row0g >> 10, t0 = row0g & 1023;
    if (n0 < 256) {
      size_t bh = (size_t)b * NHEAD + (n0 >> 6);
      int tb0 = t0 >> 4;
      #pragma unroll
      for (int fb = 0; fb < 8; ++fb) {
        int tbl = fb >> 1, kcl = fb & 1;
        int t_l = tbl * 16 + (lane2 & 15);
        int c_l = kcl * 32 + ((lane2 >> 4) << 3) + e0;
        size_t dst = ((bh * 64 + tb0 + tbl) * 2 + kcl) * 512 + lane2 * 8 + e0;
        out0[dst] = t16[t_l][c_l];
        out0[dst + 1] = t16[t_l][c_l + 1];
      }
    } else {
      size_t bh = (size_t)b * NHEAD + ((n0 - 256) >> 6);
      int jc0 = t0 >> 5;
      #pragma unroll
      for (int fb = 0; fb < 8; ++fb) {
        int dbl = fb >> 1, jcl = fb & 1;
        int c_l = dbl * 16 + (lane2 & 15);
        int t_l = jcl * 32 + ((lane2 >> 4) << 3) + e0;
        size_t dst = ((bh * 4 + dbl) * 32 + jc0 + jcl) * 512 + lane2 * 8 + e0;
        out1[dst] = t16[t_l][c_l];
        out1[dst + 1] = t16[t_l + 1][c_l];
      }
    }
  }
}

// ---------------- attention v7 (layers 0-10, D=64) ----------------
__global__ __launch_bounds__(512) void k_attn_v7(
    const unsigned short* __restrict__ q,      // fp16 frag [bh][tb 64][kc 2][512]
    const unsigned short* __restrict__ Hh,     // fp16 [b][t][64]
    const unsigned short* __restrict__ vT,     // fp16 frag [bh][db 4][jc 32][512]
    const float* __restrict__ head_mask,
    float* __restrict__ Hst, unsigned short* __restrict__ HbfOut, size_t hbPl,
    const float* __restrict__ g, const float* __restrict__ bta) {
  extern __shared__ char sh[];
  int bid = blockIdx.x;
  int xcd = bid & 7, u = bid >> 3;
  int b = xcd * 2 + (u >> 4);
  int pidx = u & 15;
  int tid = threadIdx.x;
  int wid = tid >> 6, lane = tid & 63;
  int h = wid & 3, grp = wid >> 2;
  int lr = lane & 15, lg = lane >> 4;
  int i0t[2] = { pidx * 32, (31 - pidx) * 32 };
  int NSS = (33 - pidx) >> 1;

  const char* gK = (const char*)(Hh + (size_t)b * SEQ * 64);
  char* KB = sh;
  unsigned short* sw = (unsigned short*)(sh + 16384 + wid * 2560);

  const unsigned short* qh = q + (size_t)(b * NHEAD + h) * 65536;
  const unsigned short* vh = vT + (size_t)(b * NHEAD + h) * 65536;

  f16x8 qf[2][2][2];
  #pragma unroll
  for (int t = 0; t < 2; ++t)
    #pragma unroll
    for (int mf = 0; mf < 2; ++mf)
      #pragma unroll
      for (int kf = 0; kf < 2; ++kf)
        qf[t][mf][kf] = *reinterpret_cast<const f16x8*>(
            qh + ((((i0t[t] >> 4) + mf) * 2 + kf) << 9) + lane * 8);
  f32x4 oacc[2][2][4] = {};

  u32x4 sreg;
  auto SLOAD = [&](int ss) {
    sreg = *reinterpret_cast<const u32x4*>(gK + (size_t)ss * 8192 + tid * 16);
  };
  auto SWRITE = [&](int buf) {
    int row = tid >> 3, colb = (tid & 7) * 16;
    *reinterpret_cast<u32x4*>(KB + buf * 8192 + row * 128 + (colb ^ ((row & 7) << 4))) = sreg;
  };

  SLOAD(0); SWRITE(0);
  __syncthreads();

  for (int ss = 0; ss < NSS; ++ss) {
    int cur = ss & 1;
    bool more = (ss + 1 < NSS);
    if (more) SLOAD(ss + 1);
    int js = ss * 64 + grp * 32;
    if (js < i0t[1] + 32) {
      f16x8 vch[4];
      #pragma unroll
      for (int nf = 0; nf < 4; ++nf)
        vch[nf] = *reinterpret_cast<const f16x8*>(vh + ((nf * 32 + (js >> 5)) << 9) + lane * 8);
      f16x8 kfr[2][2];
      #pragma unroll
      for (int nf2 = 0; nf2 < 2; ++nf2)
        #pragma unroll
        for (int kf = 0; kf < 2; ++kf) {
          int row = grp * 32 + nf2 * 16 + lr;
          int colb = kf * 64 + lg * 16;
          kfr[nf2][kf] = *reinterpret_cast<const f16x8*>(
              KB + cur * 8192 + row * 128 + (colb ^ ((row & 7) << 4)));
        }
      #pragma unroll
      for (int t = 0; t < 2; ++t) {
        if (js < i0t[t] + 32) {
          #pragma unroll
          for (int nf2 = 0; nf2 < 2; ++nf2) {
            #pragma unroll
            for (int mf = 0; mf < 2; ++mf) {
              f32x4 sacc = {};
              #pragma unroll
              for (int kf = 0; kf < 2; ++kf)
                sacc = __builtin_amdgcn_mfma_f32_16x16x32_f16(qf[t][mf][kf], kfr[nf2][kf], sacc, 0, 0, 0);
              #pragma unroll
              for (int r = 0; r < 4; ++r) {
                int i = i0t[t] + mf * 16 + lg * 4 + r;
                int j = js + nf2 * 16 + lr;
                float v = (j <= i) ? fmaxf(sacc[r], 0.f) : 0.f;
                sw[(mf * 16 + lg * 4 + r) * 40 + nf2 * 16 + lr] = f2h(v);
              }
            }
          }
          asm volatile("s_waitcnt lgkmcnt(0)" ::: "memory");
          __builtin_amdgcn_sched_barrier(0);
          #pragma unroll
          for (int mf = 0; mf < 2; ++mf) {
            f16x8 sf = *reinterpret_cast<const f16x8*>(&sw[(mf * 16 + lr) * 40 + lg * 8]);
            #pragma unroll
            for (int nf = 0; nf < 4; ++nf)
              oacc[t][mf][nf] = __builtin_amdgcn_mfma_f32_16x16x32_f16(sf, vch[nf], oacc[t][mf][nf], 0, 0, 0);
          }
        }
      }
    }
    if (more) SWRITE(cur ^ 1);
    __syncthreads();
  }

  float hm = head_mask[h];
  float hm3 = hm * hm * hm;
  float* f8 = (float*)sh;
  for (int t = 0; t < 2; ++t) {
    #pragma unroll
    for (int mf = 0; mf < 2; ++mf)
      #pragma unroll
      for (int nf = 0; nf < 4; ++nf)
        #pragma unroll
        for (int r = 0; r < 4; ++r)
          f8[wid * 2048 + (mf * 16 + lg * 4 + r) * 64 + nf * 16 + lr] = oacc[t][mf][nf][r] * hm3;
    __syncthreads();
    for (int idx = tid; idx < 8192; idx += 512) f8[idx] += f8[idx + 8192];
    __syncthreads();
    for (int idx = tid; idx < 4096; idx += 512) f8[idx] += f8[idx + 4096];
    __syncthreads();
    for (int idx = tid; idx < 2048; idx += 512) {
      int rr = idx >> 6;
      f8[idx] = (f8[idx] + f8[idx + 2048]) / (float)(i0t[t] + rr + 1);
    }
    __syncthreads();
    for (int rl = 0; rl < 4; ++rl) {
      int rr = wid * 4 + rl;
      size_t row = ((size_t)b * SEQ + i0t[t] + rr) * EMB;
      int c0 = lane, c1 = lane + 64;
      float x0 = Hst[row + c0];
      float x1 = Hst[row + c1] + f8[rr * 64 + lane];
      float s1 = x0 + x1, s2 = x0 * x0 + x1 * x1;
      #pragma unroll
      for (int off = 1; off < 64; off <<= 1) {
        s1 += __shfl_xor(s1, off);
        s2 += __shfl_xor(s2, off);
      }
      float mu = s1 * (1.f / 128.f);
      float var = s2 * (1.f / 128.f) - mu * mu;
      float rs = rsqrt_acc(var + LN_EPS);
      float y0 = (x0 - mu) * rs * g[c0] + bta[c0];
      float y1 = (x1 - mu) * rs * g[c1] + bta[c1];
      Hst[row + c0] = y0; Hst[row + c1] = y1;
      unsigned short h0, l0, h1, l1; split2(y0, h0, l0); split2(y1, h1, l1);
      HbfOut[row + c0] = h0; HbfOut[hbPl + row + c0] = l0;
      HbfOut[row + c1] = h1; HbfOut[hbPl + row + c1] = l1;
    }
    __syncthreads();
  }
}

// ---------------- fused attention (+LN1), last layer (DHEAD=128), parallel tree epilogue ----------------
__global__ __launch_bounds__(512) void k_attn_fused(
    const unsigned short* __restrict__ q,      // fp16 frag [bh][tb 64][kc 4][512]
    const unsigned short* __restrict__ kbuf,   // fp16 frag [bh][tb 64][kc 4][512]
    const unsigned short* __restrict__ vT,     // fp16 frag [bh][db 8][jc 32][512]
    const float* __restrict__ head_mask,
    float* __restrict__ Hst, unsigned short* __restrict__ HbfOut, size_t hbPl,
    const float* __restrict__ g, const float* __restrict__ bta) {
  constexpr int KF = 4, NFO = 8;
  constexpr int NT = SEQ / 32;
  extern __shared__ char sh[];      // attn: sw [0,20480); epilogue f8 [0,65536)
  int bid = blockIdx.x;
  int xcd = bid & 7, u = bid >> 3;
  int b = xcd * 2 + (u >> 4);
  int pidx = u & 15;
  int tid = threadIdx.x;
  int wid = tid >> 6, lane = tid & 63;
  int h = wid & 3, grp = wid >> 2;
  int lr = lane & 15, lg = lane >> 4;
  unsigned short* sw = (unsigned short*)(sh + wid * 2560);
  const unsigned short* qh = q + (size_t)(b * NHEAD + h) * 131072;
  const unsigned short* kh = kbuf + (size_t)(b * NHEAD + h) * 131072;
  const unsigned short* vh = vT + (size_t)(b * NHEAD + h) * 131072;
  float hm = head_mask[h];
  float hm3 = hm * hm * hm;

  for (int s = 0; s < 2; ++s) {
    int tile = (s == 0) ? pidx : (NT - 1 - pidx);
    int i0 = tile * 32;
    f16x8 qf[2][KF];
    #pragma unroll
    for (int mf = 0; mf < 2; ++mf)
      #pragma unroll
      for (int kf = 0; kf < KF; ++kf)
        qf[mf][kf] = *reinterpret_cast<const f16x8*>(
            qh + ((((i0 >> 4) + mf) * 4 + kf) << 9) + lane * 8);
    f32x4 oacc[2][NFO] = {};
    int jend = i0 + 32;
    for (int j0 = grp * 32; j0 < jend; j0 += 64) {
      f16x8 vch[NFO];
      #pragma unroll
      for (int nf = 0; nf < NFO; ++nf)
        vch[nf] = *reinterpret_cast<const f16x8*>(vh + ((nf * 32 + (j0 >> 5)) << 9) + lane * 8);
      #pragma unroll
      for (int nf2 = 0; nf2 < 2; ++nf2) {
        f16x8 kfr[KF];
        #pragma unroll
        for (int kf = 0; kf < KF; ++kf)
          kfr[kf] = *reinterpret_cast<const f16x8*>(
              kh + ((((j0 >> 4) + nf2) * 4 + kf) << 9) + lane * 8);
        #pragma unroll
        for (int mf = 0; mf < 2; ++mf) {
          f32x4 sacc = {};
          #pragma unroll
          for (int kf = 0; kf < KF; ++kf)
            sacc = __builtin_amdgcn_mfma_f32_16x16x32_f16(qf[mf][kf], kfr[kf], sacc, 0, 0, 0);
          #pragma unroll
          for (int r = 0; r < 4; ++r) {
            int i = i0 + mf * 16 + lg * 4 + r;
            int j = j0 + nf2 * 16 + lr;
            float v = (j <= i) ? fmaxf(sacc[r], 0.f) : 0.f;
            sw[(mf * 16 + lg * 4 + r) * 40 + nf2 * 16 + lr] = f2h(v);
          }
        }
      }
      asm volatile("s_waitcnt lgkmcnt(0)" ::: "memory");
      __builtin_amdgcn_sched_barrier(0);
      #pragma unroll
      for (int mf = 0; mf < 2; ++mf) {
        f16x8 sf = *reinterpret_cast<const f16x8*>(&sw[(mf * 16 + lr) * 40 + lg * 8]);
        #pragma unroll
        for (int nf = 0; nf < NFO; ++nf)
          oacc[mf][nf] = __builtin_amdgcn_mfma_f32_16x16x32_f16(sf, vch[nf], oacc[mf][nf], 0, 0, 0);
      }
    }
    // ---- parallel tree head-sum: f8[4 regions][32][128] ----
    float* f8 = (float*)sh;
    __syncthreads();
    if (wid < 4) {
      #pragma unroll
      for (int mf = 0; mf < 2; ++mf)
        #pragma unroll
        for (int nf = 0; nf < NFO; ++nf)
          #pragma unroll
          for (int r = 0; r < 4; ++r)
            f8[(wid & 3) * 4096 + (mf * 16 + lg * 4 + r) * 128 + nf * 16 + lr] = oacc[mf][nf][r] * hm3;
    }
    __syncthreads();
    if (wid >= 4) {
      #pragma unroll
      for (int mf = 0; mf < 2; ++mf)
        #pragma unroll
        for (int nf = 0; nf < NFO; ++nf)
          #pragma unroll
          for (int r = 0; r < 4; ++r)
            f8[(wid & 3) * 4096 + (mf * 16 + lg * 4 + r) * 128 + nf * 16 + lr] += oacc[mf][nf][r] * hm3;
    }
    __syncthreads();
    for (int idx = tid; idx < 8192; idx += 512) f8[idx] += f8[idx + 8192];
    __syncthreads();
    for (int idx = tid; idx < 4096; idx += 512) {
      int rr = idx >> 7;
      f8[idx] = (f8[idx] + f8[idx + 4096]) / (float)(i0 + rr + 1);
    }
    __syncthreads();
    for (int rl = 0; rl < 4; ++rl) {
      int rr = wid * 4 + rl;
      size_t row = ((size_t)b * SEQ + i0 + rr) * EMB;
      int c0 = lane, c1 = lane + 64;
      float x0 = Hst[row + c0] + f8[rr * 128 + c0];
      float x1 = Hst[row + c1] + f8[rr * 128 + c1];
      float s1 = x0 + x1, s2 = x0 * x0 + x1 * x1;
      #pragma unroll
      for (int off = 1; off < 64; off <<= 1) {
        s1 += __shfl_xor(s1, off);
        s2 += __shfl_xor(s2, off);
      }
      float mu = s1 * (1.f / 128.f);
      float var = s2 * (1.f / 128.f) - mu * mu;
      float rs = rsqrt_acc(var + LN_EPS);
      float y0 = (x0 - mu) * rs * g[c0] + bta[c0];
      float y1 = (x1 - mu) * rs * g[c1] + bta[c1];
      Hst[row + c0] = y0; Hst[row + c1] = y1;
      unsigned short h0, l0, h1, l1; split2(y0, h0, l0); split2(y1, h1, l1);
      HbfOut[row + c0] = h0; HbfOut[hbPl + row + c0] = l0;
      HbfOut[row + c1] = h1; HbfOut[hbPl + row + c1] = l1;
    }
    __syncthreads();
  }
}

// ---------------- fused MLP2 + residual + LN2 (+next-layer qv projection) ----------------
// NEXT=3: also compute next layer's q/v fp16 frags from y (LDS-staged split planes).
// NEXT=-1: mlp2+LN2 only.
template<int NEXT>
__global__ __launch_bounds__(256) void k_mlp2qv(
    const unsigned short* __restrict__ A,      // mid frag u32
    const unsigned short* __restrict__ BT, size_t bPl, const float* __restrict__ bias,
    float* __restrict__ Hst, unsigned short* __restrict__ HbfOut, size_t hbPl,
    unsigned short* __restrict__ Hh,
    const float* __restrict__ g, const float* __restrict__ bta,
    const unsigned short* __restrict__ QW, size_t qwPl,
    unsigned short* __restrict__ qOut, unsigned short* __restrict__ vOut) {
  extern __shared__ unsigned short mlds[];  // y planes [64][136]x2 = 17408 u16; staging after
  int tid = threadIdx.x;
  int wid = tid >> 6, lane = tid & 63;
  int lr = lane & 15, lg = lane >> 4;
  int row0g = blockIdx.x * 64;
  int row0 = row0g + wid * 16;
  f32x4 acc[8] = {};
  const unsigned int* aF = (const unsigned int*)A + (size_t)(blockIdx.x * 4 + wid) * 8192 + lane * 8;
  #pragma unroll
  for (int kc = 0; kc < 16; ++kc) {
    u32x4 pa = *reinterpret_cast<const u32x4*>(aF + kc * 512);
    u32x4 pb = *reinterpret_cast<const u32x4*>(aF + kc * 512 + 4);
    bf16x8 ah, al;
    #pragma unroll
    for (int j = 0; j < 4; ++j) {
      ah[j] = (short)(pa[j] & 0xffff);  al[j] = (short)(pa[j] >> 16);
      ah[4 + j] = (short)(pb[j] & 0xffff);  al[4 + j] = (short)(pb[j] >> 16);
    }
    #pragma unroll
    for (int nf = 0; nf < 8; ++nf) {
      size_t bo = ((size_t)kc * 8 + nf) * 512 + lane * 8;
      bf16x8 bh = *reinterpret_cast<const bf16x8*>(BT + bo);
      bf16x8 bl = *reinterpret_cast<const bf16x8*>(BT + bPl + bo);
      acc[nf] = __builtin_amdgcn_mfma_f32_16x16x32_bf16(ah, bh, acc[nf], 0, 0, 0);
      acc[nf] = __builtin_amdgcn_mfma_f32_16x16x32_bf16(al, bh, acc[nf], 0, 0, 0);
      acc[nf] = __builtin_amdgcn_mfma_f32_16x16x32_bf16(ah, bl, acc[nf], 0, 0, 0);
    }
  }
  int rowb = row0 + lg * 4;
  float xv[8][4];
  float s1[4] = {}, s2[4] = {};
  #pragma unroll
  for (int nf = 0; nf < 8; ++nf) {
    int c = nf * 16 + lr;
    float bv = bias[c];
    #pragma unroll
    for (int r = 0; r < 4; ++r) {
      float x = acc[nf][r] + bv + Hst[(size_t)(rowb + r) * EMB + c];
      xv[nf][r] = x; s1[r] += x; s2[r] += x * x;
    }
  }
  #pragma unroll
  for (int off = 1; off < 16; off <<= 1) {
    #pragma unroll
    for (int r = 0; r < 4; ++r) {
      s1[r] += __shfl_xor(s1[r], off);
      s2[r] += __shfl_xor(s2[r], off);
    }
  }
  #pragma unroll
  for (int r = 0; r < 4; ++r) {
    float mu = s1[r] * (1.f / 128.f);
    float var = s2[r] * (1.f / 128.f) - mu * mu;
    float rs = rsqrt_acc(var + LN_EPS);
    #pragma unroll
    for (int nf = 0; nf < 8; ++nf) {
      int c = nf * 16 + lr;
      float y = (xv[nf][r] - mu) * rs * g[c] + bta[c];
      size_t o = (size_t)(rowb + r) * EMB + c;
      Hst[o] = y;
      unsigned short hi, lo; split2(y, hi, lo);
      HbfOut[o] = hi; HbfOut[hbPl + o] = lo;
      if (c < 64) Hh[(size_t)(rowb + r) * 64 + c] = f2h(y);
      if (NEXT != -1) {
        int lrow = wid * 16 + lg * 4 + r;
        mlds[lrow * 136 + c] = hi;
        mlds[64 * 136 + lrow * 136 + c] = lo;
      }
    }
  }
  if (NEXT == -1) return;
  __syncthreads();
  // ---- phase 2: qv projection for next layer (A = y planes in LDS, B = QW frags) ----
  bf16x8 afh[4], afl[4];
  #pragma unroll
  for (int kf = 0; kf < 4; ++kf) {
    int o = (wid * 16 + lr) * 136 + kf * 32 + lg * 8;
    afh[kf] = *reinterpret_cast<const bf16x8*>(mlds + o);
    afl[kf] = *reinterpret_cast<const bf16x8*>(mlds + 64 * 136 + o);
  }
  unsigned short (*stg)[66] = (unsigned short(*)[66])(mlds + 2 * 64 * 136);
  int b = row0g >> 10, t0 = row0g & 1023;
  int u2 = tid * 2;
  int lane2 = u2 >> 3, e0 = u2 & 7;
  for (int t = 0; t < 8; ++t) {
    int n0 = t * 64;
    f32x4 qa[4] = {};
    #pragma unroll
    for (int nf = 0; nf < 4; ++nf) {
      #pragma unroll
      for (int kf = 0; kf < 4; ++kf) {
        size_t bo = ((size_t)kf * 32 + (n0 >> 4) + nf) * 512 + lane * 8;
        bf16x8 bh = *reinterpret_cast<const bf16x8*>(QW + bo);
        bf16x8 bl = *reinterpret_cast<const bf16x8*>(QW + qwPl + bo);
        qa[nf] = __builtin_amdgcn_mfma_f32_16x16x32_bf16(afh[kf], bh, qa[nf], 0, 0, 0);
        qa[nf] = __builtin_amdgcn_mfma_f32_16x16x32_bf16(afl[kf], bh, qa[nf], 0, 0, 0);
        qa[nf] = __builtin_amdgcn_mfma_f32_16x16x32_bf16(afh[kf], bl, qa[nf], 0, 0, 0);
      }
    }
    #pragma unroll
    for (int nf = 0; nf < 4; ++nf)
      #pragma unroll
      for (int r = 0; r < 4; ++r)
        stg[wid * 16 + lg * 4 + r][nf * 16 + lr] = f2h(qa[nf][r]);
    __syncthreads();
    if (n0 < 256) {
      size_t bh = (size_t)b * NHEAD + (n0 >> 6);
      int tb0 = t0 >> 4;
      int kc0l = (n0 >> 5) & 1;   // local kc within head (0 or 1)
      #pragma unroll
      for (int fb = 0; fb < 8; ++fb) {
        int tbl = fb >> 1, kcl = fb & 1;
        int t_l = tbl * 16 + (lane2 & 15);
        int c_l = kcl * 32 + ((lane2 >> 4) << 3) + e0;
        size_t dst = ((bh * 64 + tb0 + tbl) * 2 + kcl) * 512 + lane2 * 8 + e0;
        qOut[dst] = stg[t_l][c_l];
        qOut[dst + 1] = stg[t_l][c_l + 1];
      }
      (void)kc0l;
    } else {
      size_t bh = (size_t)b * NHEAD + ((n0 - 256) >> 6);
      int jc0 = t0 >> 5;
      #pragma unroll
      for (int fb = 0; fb < 8; ++fb) {
        int dbl = fb >> 1, jcl = fb & 1;
        int c_l = dbl * 16 + (lane2 & 15);
        int t_l = jcl * 32 + ((lane2 >> 4) << 3) + e0;
        size_t dst = ((bh * 4 + dbl) * 32 + jc0 + jcl) * 512 + lane2 * 8 + e0;
        vOut[dst] = stg[t_l][c_l];
        vOut[dst + 1] = stg[t_l + 1][c_l];
      }
    }
    __syncthreads();
  }
}

// ---------------- readout ----------------
__global__ __launch_bounds__(64) void k_readout(const float* __restrict__ H,
                                                const float* __restrict__ W, const float* __restrict__ b0,
                                                float* __restrict__ out) {
  int idx = blockIdx.x;           // b*512 + p
  int b = idx >> 9, p = idx & 511;
  size_t row = ((size_t)b * SEQ + 2 * p) * EMB;
  int lane = threadIdx.x;
  float acc = H[row + lane] * W[lane] + H[row + 64 + lane] * W[64 + lane];
  #pragma unroll
  for (int off = 1; off < 64; off <<= 1) acc += __shfl_xor(acc, off);
  if (lane == 0) out[idx] = acc + b0[0];
}

extern "C" void kernel_launch(void* const* d_in, const int* in_sizes, int n_in,
                              void* d_out, int out_size, void* d_ws, size_t ws_size,
                              hipStream_t stream) {
  (void)in_sizes; (void)n_in; (void)out_size; (void)ws_size;
  const float* xs        = (const float*)d_in[0];
  const float* ys        = (const float*)d_in[1];
  const float* head_mask = (const float*)d_in[2];
  const float* read_in_W = (const float*)d_in[3];
  const float* read_in_b = (const float*)d_in[4];
  const float* qW        = (const float*)d_in[5];
  const float* vW        = (const float*)d_in[6];
  const float* qW_last   = (const float*)d_in[7];
  const float* kW_last   = (const float*)d_in[8];
  const float* vW_last   = (const float*)d_in[9];
  const float* ln1_g     = (const float*)d_in[10];
  const float* ln1_b     = (const float*)d_in[11];
  const float* ln2_g     = (const float*)d_in[12];
  const float* ln2_b     = (const float*)d_in[13];
  const float* mlp_W1    = (const float*)d_in[14];
  const float* mlp_b1    = (const float*)d_in[15];
  const float* mlp_W2    = (const float*)d_in[16];
  const float* mlp_b2    = (const float*)d_in[17];
  const float* ro_W      = (const float*)d_in[18];
  const float* ro_b      = (const float*)d_in[19];

  const size_t HPL   = (size_t)BS * SEQ * EMB;          // 2M
  const size_t QVWPL = (size_t)11 * 512 * 128;
  const size_t W1PL  = (size_t)12 * 512 * 128;
  const size_t W2PL  = (size_t)12 * 512 * 128;
  const size_t LASTPL= (size_t)1536 * 128;
  const size_t VOFF  = (size_t)BS * NHEAD * 65536;      // v region inside qbuf

  char* ws = (char*)d_ws;
  size_t off = 0;
  auto alloc = [&](size_t bytes) -> void* {
    void* p = ws + off;
    off += (bytes + 255) & ~(size_t)255;
    return p;
  };
  float* H             = (float*)alloc(HPL * 4);                  // 8 MB
  unsigned short* Hbf  = (unsigned short*)alloc(2 * HPL * 2);     // 8 MB
  unsigned short* Hbf2 = (unsigned short*)alloc(2 * HPL * 2);     // 8 MB
  unsigned short* Hh   = (unsigned short*)alloc((size_t)BS * SEQ * 64 * 2);  // 2 MB
  unsigned short* qbuf = (unsigned short*)alloc((size_t)BS * NHEAD * 131072 * 2); // 16.8 MB (q | v for v7; q-last)
  unsigned short* kmid = (unsigned short*)alloc((size_t)BS * SEQ * 512 * 4);  // 33.5 MB (mid / k-last frag)
  unsigned short* vTl  = (unsigned short*)alloc((size_t)BS * NHEAD * 131072 * 2); // 16.8 MB (last v frag)
  unsigned short* qvWT = (unsigned short*)alloc(2 * QVWPL * 2);
  unsigned short* W1T  = (unsigned short*)alloc(2 * W1PL * 2);
  unsigned short* W2T  = (unsigned short*)alloc(2 * W2PL * 2);
  unsigned short* lastT= (unsigned short*)alloc(2 * LASTPL * 2);

  { int tot = 11 * 512 * 128; k_prep_qvfrag<<<dim3((tot + 255) / 256), 256, 0, stream>>>(qW, vW, qvWT, QVWPL); }
  { int tot = 12 * 512 * 128; k_prep_fragT<<<dim3((tot + 255) / 256), 256, 0, stream>>>(mlp_W1, W1T, W1PL, 12, 128, 512, 512, 128); }
  { int tot = 12 * 512 * 128; k_prep_fragT<<<dim3((tot + 255) / 256), 256, 0, stream>>>(mlp_W2, W2T, W2PL, 12, 512, 128, 128, 512); }
  { int tot = 1536 * 128; k_prep_lastfrag<<<dim3((tot + 255) / 256), 256, 0, stream>>>(qW_last, kW_last, vW_last, lastT, LASTPL); }

  k_combine_readin<<<dim3(BS * SEQ), 128, 0, stream>>>(xs, ys, read_in_W, read_in_b, H, Hbf, HPL, Hh);

  const int GEMM_LDS = 2 * 64 * 136 * 2;            // 34816 B
  const int MLDS = (2 * 64 * 136 + 64 * 66) * 2;    // 43264 B
  // layer-0 qv projection (A = Hbf)
  k_gemm<3, false><<<dim3(256, 8), 256, GEMM_LDS, stream>>>(
      Hbf, HPL, qvWT, QVWPL, nullptr, 512, qbuf, qbuf + VOFF, nullptr);

  for (int l = 0; l < 11; ++l) {
    k_attn_v7<<<dim3(256), 512, 65536, stream>>>(
        qbuf, Hh, qbuf + VOFF, head_mask, H, Hbf2, HPL, ln1_g + l * 128, ln1_b + l * 128);
    k_gemm<0, true><<<dim3(256, 8), 256, GEMM_LDS, stream>>>(
        Hbf2, HPL, W1T + (size_t)l * 65536, W1PL, mlp_b1 + l * 512, 512,
        kmid, nullptr, nullptr);
    if (l < 10)
      k_mlp2qv<3><<<dim3(256), 256, MLDS, stream>>>(
          kmid, W2T + (size_t)l * 65536, W2PL, mlp_b2 + l * 128,
          H, Hbf, HPL, Hh, ln2_g + l * 128, ln2_b + l * 128,
          qvWT + (size_t)(l + 1) * 65536, QVWPL, qbuf, qbuf + VOFF);
    else
      k_mlp2qv<-1><<<dim3(256), 256, 0, stream>>>(
          kmid, W2T + (size_t)l * 65536, W2PL, mlp_b2 + l * 128,
          H, Hbf, HPL, Hh, ln2_g + l * 128, ln2_b + l * 128,
          nullptr, 0, nullptr, nullptr);
  }
  // last layer: qkv frag projections (A = Hbf), attention+LN1, MLP, LN2
  k_gemm<2, false><<<dim3(256, 24), 256, GEMM_LDS, stream>>>(
      Hbf, HPL, lastT, LASTPL, nullptr, 1536, qbuf, kmid, vTl);
  k_attn_fused<<<dim3(256), 512, 65536, stream>>>(
      qbuf, kmid, vTl, head_mask, H, Hbf2, HPL, ln1_g + 11 * 128, ln1_b + 11 * 128);
  k_gemm<0, true><<<dim3(256, 8), 256, GEMM_LDS, stream>>>(
      Hbf2, HPL, W1T + (size_t)11 * 65536, W1PL, mlp_b1 + 11 * 512, 512,
      kmid, nullptr, nullptr);
  k_mlp2qv<-1><<<dim3(256), 256, 0, stream>>>(
      kmid, W2T + (size_t)11 * 65536, W2PL, mlp_b2 + 11 * 128,
      H, Hbf, HPL, Hh, ln2_g + 11 * 128, ln2_b + 11 * 128,
      nullptr, 0, nullptr, nullptr);

  k_readout<<<dim3(8192), 64, 0, stream>>>(H, ro_W, ro_b, (float*)d_out);
}

// Round 12
// 1143.849 us; speedup vs baseline: 1.1262x; 1.1262x over previous
//
#include <hip/hip_runtime.h>

#define BS 16
#define SEQ 1024
#define EMB 128
#define NHEAD 4
#define LN_EPS 1e-5f

typedef __attribute__((ext_vector_type(8))) short bf16x8;
typedef __attribute__((ext_vector_type(8))) _Float16 f16x8;
typedef __attribute__((ext_vector_type(4))) float f32x4;
typedef __attribute__((ext_vector_type(4))) unsigned short u16x4;
typedef __attribute__((ext_vector_type(4))) unsigned int u32x4;

__device__ __forceinline__ unsigned short f2b(float f) {
  union { float f; unsigned u; } v; v.f = f;
  unsigned r = v.u + 0x7fff + ((v.u >> 16) & 1);
  return (unsigned short)(r >> 16);
}
__device__ __forceinline__ unsigned short f2h(float f) {
  union { _Float16 h; unsigned short u; } v; v.h = (_Float16)f; return v.u;
}
// split x into hi+lo bf16 (3-term Markidis precision: rel err ~2^-17)
__device__ __forceinline__ void split2(float x, unsigned short& hi, unsigned short& lo) {
  unsigned short h = f2b(x);
  float hf = __uint_as_float((unsigned)h << 16);
  hi = h; lo = f2b(x - hf);
}
__device__ __forceinline__ float rsqrt_acc(float v) {
  float r = rsqrtf(v);
  return r * (1.5f - 0.5f * v * r * r);   // one Newton step -> ~f32-exact
}

// ---------------- weight prep: fragment-ordered 2-plane bf16 ----------------
__global__ void k_prep_fragT(const float* __restrict__ in, unsigned short* __restrict__ out,
                             size_t PL, int L, int Kin, int Nin, int N, int K) {
  int idx = blockIdx.x * 256 + threadIdx.x;
  int nblk = (N >> 4) * (K >> 5);
  int total = L * N * K;
  if (idx >= total) return;
  int e = idx & 7;
  int lane = (idx >> 3) & 63;
  int blk = (idx >> 9) % nblk;
  int l = idx / (512 * nblk);
  int nb = blk % (N >> 4), kc = blk / (N >> 4);
  int n = nb * 16 + (lane & 15);
  int k = kc * 32 + (lane >> 4) * 8 + e;
  float v = (k < Kin && n < Nin) ? in[(size_t)l * Kin * Nin + (size_t)k * Nin + n] : 0.f;
  unsigned short hi, lo; split2(v, hi, lo);
  out[idx] = hi; out[PL + idx] = lo;
}

// qvW frag: N=512, K=128; n<256 q side (h=n>>6,d=n&63, d63 zero), else v side
__global__ void k_prep_qvfrag(const float* __restrict__ qW, const float* __restrict__ vW,
                              unsigned short* __restrict__ out, size_t PL) {
  int idx = blockIdx.x * 256 + threadIdx.x;
  int total = 11 * 512 * 128;
  if (idx >= total) return;
  int e = idx & 7;
  int lane = (idx >> 3) & 63;
  int blk = (idx >> 9) & 127;       // kc*32 + nb
  int l = idx >> 16;
  int nb = blk & 31, kc = blk >> 5;
  int n = nb * 16 + (lane & 15);
  int k = kc * 32 + (lane >> 4) * 8 + e;
  float v = 0.f;
  if (n < 256) {
    int hh = n >> 6, d = n & 63;
    if (d < 63 && k >= 64 && k < 127) v = qW[(size_t)l * 63 * 252 + (size_t)(k - 64) * 252 + hh * 63 + d];
  } else {
    int n2 = n - 256, hh = n2 >> 6, d = n2 & 63;
    if (d < 63 && k < 63) v = vW[(size_t)l * 63 * 252 + (size_t)k * 252 + hh * 63 + d];
  }
  unsigned short hi, lo; split2(v, hi, lo);
  out[idx] = hi; out[PL + idx] = lo;
}

// last-layer qkv frag: N=1536, K=128
__global__ void k_prep_lastfrag(const float* __restrict__ qW, const float* __restrict__ kW,
                                const float* __restrict__ vW,
                                unsigned short* __restrict__ out, size_t PL) {
  int idx = blockIdx.x * 256 + threadIdx.x;
  int total = 1536 * 128;
  if (idx >= total) return;
  int e = idx & 7;
  int lane = (idx >> 3) & 63;
  int blk = idx >> 9;               // kc*96 + nb
  int nb = blk % 96, kc = blk / 96;
  int n = nb * 16 + (lane & 15);
  int k = kc * 32 + (lane >> 4) * 8 + e;
  int tsel = n >> 9, n2 = n & 511;
  const float* W = tsel == 0 ? qW : (tsel == 1 ? kW : vW);
  float v = W[(size_t)k * 512 + n2];
  unsigned short hi, lo; split2(v, hi, lo);
  out[idx] = hi; out[PL + idx] = lo;
}

// ---------------- combine + read_in ----------------
__global__ void k_combine_readin(const float* __restrict__ xs, const float* __restrict__ ys,
                                 const float* __restrict__ W, const float* __restrict__ bias,
                                 float* __restrict__ H, unsigned short* __restrict__ Hbf, size_t hbPl,
                                 unsigned short* __restrict__ Hh) {
  int blk = blockIdx.x;            // b*1024 + t
  int b = blk >> 10, t = blk & 1023, p = t >> 1;
  __shared__ float zs[64];
  int tid = threadIdx.x;           // 128
  if (tid < 64) {
    float v;
    if (tid < 63) v = xs[((size_t)b * 512 + p) * 63 + tid];
    else v = (t & 1) ? ys[(size_t)b * 512 + p] : 0.f;
    zs[tid] = v;
  }
  __syncthreads();
  float acc = bias[tid];
  #pragma unroll 8
  for (int d = 0; d < 64; ++d) acc += zs[d] * W[d * 128 + tid];
  size_t o = (size_t)blk * 128 + tid;
  H[o] = acc;
  unsigned short hi, lo; split2(acc, hi, lo);
  Hbf[o] = hi; Hbf[hbPl + o] = lo;
  if (tid < 64) Hh[(size_t)blk * 64 + tid] = f2h(acc);  // fp16 K image (dims 0..63)
}

// ---------------- split-precision MFMA GEMM: A LDS-staged, B fragment-ordered ----------------
// MODE 2: last qkv frag fp16; MODE 3: qv frag fp16
template<int MODE, bool RELU>
__global__ __launch_bounds__(256) void k_gemm(
    const unsigned short* __restrict__ A, size_t aPl,
    const unsigned short* __restrict__ BT, size_t bPl, const float* __restrict__ bias,
    int N,
    unsigned short* __restrict__ out0,
    unsigned short* __restrict__ out1,
    unsigned short* __restrict__ out2) {
  extern __shared__ unsigned short lds[];   // A 2 planes [64][136] = 34816 B; tile reuse
  int tid = threadIdx.x;
  int wid = tid >> 6, lane = tid & 63;
  int lr = lane & 15, lg = lane >> 4;
  int row0g = blockIdx.x * 64;
  int n0 = blockIdx.y * 64;
  unsigned short* Ah = lds;
  unsigned short* Al = Ah + 64 * 136;
  {
    const unsigned short* gA = A + (size_t)row0g * 128;
    const unsigned short* srcs[2] = { gA, gA + aPl };
    unsigned short* dsts[2] = { Ah, Al };
    #pragma unroll
    for (int p = 0; p < 2; ++p)
      #pragma unroll
      for (int it = 0; it < 4; ++it) {
        int e = it * 2048 + tid * 8;
        bf16x8 v = *reinterpret_cast<const bf16x8*>(srcs[p] + e);
        *reinterpret_cast<bf16x8*>(dsts[p] + (e >> 7) * 136 + (e & 127)) = v;
      }
  }
  __syncthreads();
  bf16x8 afh[4], afl[4];
  #pragma unroll
  for (int kf = 0; kf < 4; ++kf) {
    int o = (wid * 16 + lr) * 136 + kf * 32 + lg * 8;
    afh[kf] = *reinterpret_cast<const bf16x8*>(Ah + o);
    afl[kf] = *reinterpret_cast<const bf16x8*>(Al + o);
  }
  f32x4 acc[4] = {};
  int nhw = N >> 4;
  #pragma unroll
  for (int nf = 0; nf < 4; ++nf) {
    #pragma unroll
    for (int kf = 0; kf < 4; ++kf) {
      size_t bo = ((size_t)kf * nhw + (n0 >> 4) + nf) * 512 + lane * 8;
      bf16x8 bh = *reinterpret_cast<const bf16x8*>(BT + bo);
      bf16x8 bl = *reinterpret_cast<const bf16x8*>(BT + bPl + bo);
      acc[nf] = __builtin_amdgcn_mfma_f32_16x16x32_bf16(afh[kf], bh, acc[nf], 0, 0, 0);
      acc[nf] = __builtin_amdgcn_mfma_f32_16x16x32_bf16(afl[kf], bh, acc[nf], 0, 0, 0);
      acc[nf] = __builtin_amdgcn_mfma_f32_16x16x32_bf16(afh[kf], bl, acc[nf], 0, 0, 0);
    }
  }
  __syncthreads();   // done with staged A; reuse lds for the output tile
  #pragma unroll
  for (int nf = 0; nf < 4; ++nf) {
    int c = n0 + nf * 16 + lr;
    float bv = bias ? bias[c] : 0.f;
    #pragma unroll
    for (int r = 0; r < 4; ++r) {
      float v = acc[nf][r] + bv;
      if (RELU) v = fmaxf(v, 0.f);
      int rL = wid * 16 + lg * 4 + r, cL = nf * 16 + lr;
      ((unsigned short(*)[66])lds)[rL][cL] = f2h(v);
    }
  }
  __syncthreads();
  int u = tid * 2;
  int lane2 = u >> 3, e0 = u & 7;
  if (MODE == 2) {
    unsigned short (*t16)[66] = (unsigned short(*)[66])lds;
    int b = row0g >> 10, t0 = row0g & 1023;
    int tsel = n0 >> 9, c2b = n0 & 511, hh = c2b >> 7, dbase = c2b & 127;
    size_t bh = (size_t)b * NHEAD + hh;
    if (tsel < 2) {
      unsigned short* base = tsel ? out1 : out0;
      int tb0 = t0 >> 4, kc0 = dbase >> 5;
      #pragma unroll
      for (int fb = 0; fb < 8; ++fb) {
        int tbl = fb >> 1, kcl = fb & 1;
        int t_l = tbl * 16 + (lane2 & 15);
        int c_l = kcl * 32 + ((lane2 >> 4) << 3) + e0;
        size_t dst = ((bh * 64 + tb0 + tbl) * 4 + kc0 + kcl) * 512 + lane2 * 8 + e0;
        base[dst] = t16[t_l][c_l];
        base[dst + 1] = t16[t_l][c_l + 1];
      }
    } else {
      int db0 = dbase >> 4, jc0 = t0 >> 5;
      #pragma unroll
      for (int fb = 0; fb < 8; ++fb) {
        int dbl = fb >> 1, jcl = fb & 1;
        int c_l = dbl * 16 + (lane2 & 15);
        int t_l = jcl * 32 + ((lane2 >> 4) << 3) + e0;
        size_t dst = ((bh * 8 + db0 + dbl) * 32 + jc0 + jcl) * 512 + lane2 * 8 + e0;
        out2[dst] = t16[t_l][c_l];
        out2[dst + 1] = t16[t_l + 1][c_l];
      }
    }
  } else {  // MODE 3
    unsigned short (*t16)[66] = (unsigned short(*)[66])lds;
    int b = row0g >> 10, t0 = row0g & 1023;
    if (n0 < 256) {
      size_t bh = (size_t)b * NHEAD + (n0 >> 6);
      int tb0 = t0 >> 4;
      #pragma unroll
      for (int fb = 0; fb < 8; ++fb) {
        int tbl = fb >> 1, kcl = fb & 1;
        int t_l = tbl * 16 + (lane2 & 15);
        int c_l = kcl * 32 + ((lane2 >> 4) << 3) + e0;
        size_t dst = ((bh * 64 + tb0 + tbl) * 2 + kcl) * 512 + lane2 * 8 + e0;
        out0[dst] = t16[t_l][c_l];
        out0[dst + 1] = t16[t_l][c_l + 1];
      }
    } else {
      size_t bh = (size_t)b * NHEAD + ((n0 - 256) >> 6);
      int jc0 = t0 >> 5;
      #pragma unroll
      for (int fb = 0; fb < 8; ++fb) {
        int dbl = fb >> 1, jcl = fb & 1;
        int c_l = dbl * 16 + (lane2 & 15);
        int t_l = jcl * 32 + ((lane2 >> 4) << 3) + e0;
        size_t dst = ((bh * 4 + dbl) * 32 + jc0 + jcl) * 512 + lane2 * 8 + e0;
        out1[dst] = t16[t_l][c_l];
        out1[dst + 1] = t16[t_l + 1][c_l];
      }
    }
  }
}

// ---------------- attention v7 (layers 0-10, D=64) ----------------
__global__ __launch_bounds__(512) void k_attn_v7(
    const unsigned short* __restrict__ q,      // fp16 frag [bh][tb 64][kc 2][512]
    const unsigned short* __restrict__ Hh,     // fp16 [b][t][64]
    const unsigned short* __restrict__ vT,     // fp16 frag [bh][db 4][jc 32][512]
    const float* __restrict__ head_mask,
    float* __restrict__ Hst, unsigned short* __restrict__ HbfOut, size_t hbPl,
    const float* __restrict__ g, const float* __restrict__ bta) {
  extern __shared__ char sh[];
  int bid = blockIdx.x;
  int xcd = bid & 7, u = bid >> 3;
  int b = xcd * 2 + (u >> 4);
  int pidx = u & 15;
  int tid = threadIdx.x;
  int wid = tid >> 6, lane = tid & 63;
  int h = wid & 3, grp = wid >> 2;
  int lr = lane & 15, lg = lane >> 4;
  int i0t[2] = { pidx * 32, (31 - pidx) * 32 };
  int NSS = (33 - pidx) >> 1;

  const char* gK = (const char*)(Hh + (size_t)b * SEQ * 64);
  char* KB = sh;
  unsigned short* sw = (unsigned short*)(sh + 16384 + wid * 2560);

  const unsigned short* qh = q + (size_t)(b * NHEAD + h) * 65536;
  const unsigned short* vh = vT + (size_t)(b * NHEAD + h) * 65536;

  f16x8 qf[2][2][2];
  #pragma unroll
  for (int t = 0; t < 2; ++t)
    #pragma unroll
    for (int mf = 0; mf < 2; ++mf)
      #pragma unroll
      for (int kf = 0; kf < 2; ++kf)
        qf[t][mf][kf] = *reinterpret_cast<const f16x8*>(
            qh + ((((i0t[t] >> 4) + mf) * 2 + kf) << 9) + lane * 8);
  f32x4 oacc[2][2][4] = {};

  u32x4 sreg;
  auto SLOAD = [&](int ss) {
    sreg = *reinterpret_cast<const u32x4*>(gK + (size_t)ss * 8192 + tid * 16);
  };
  auto SWRITE = [&](int buf) {
    int row = tid >> 3, colb = (tid & 7) * 16;
    *reinterpret_cast<u32x4*>(KB + buf * 8192 + row * 128 + (colb ^ ((row & 7) << 4))) = sreg;
  };

  SLOAD(0); SWRITE(0);
  __syncthreads();

  for (int ss = 0; ss < NSS; ++ss) {
    int cur = ss & 1;
    bool more = (ss + 1 < NSS);
    if (more) SLOAD(ss + 1);
    int js = ss * 64 + grp * 32;
    if (js < i0t[1] + 32) {
      f16x8 vch[4];
      #pragma unroll
      for (int nf = 0; nf < 4; ++nf)
        vch[nf] = *reinterpret_cast<const f16x8*>(vh + ((nf * 32 + (js >> 5)) << 9) + lane * 8);
      f16x8 kfr[2][2];
      #pragma unroll
      for (int nf2 = 0; nf2 < 2; ++nf2)
        #pragma unroll
        for (int kf = 0; kf < 2; ++kf) {
          int row = grp * 32 + nf2 * 16 + lr;
          int colb = kf * 64 + lg * 16;
          kfr[nf2][kf] = *reinterpret_cast<const f16x8*>(
              KB + cur * 8192 + row * 128 + (colb ^ ((row & 7) << 4)));
        }
      #pragma unroll
      for (int t = 0; t < 2; ++t) {
        if (js < i0t[t] + 32) {
          #pragma unroll
          for (int nf2 = 0; nf2 < 2; ++nf2) {
            #pragma unroll
            for (int mf = 0; mf < 2; ++mf) {
              f32x4 sacc = {};
              #pragma unroll
              for (int kf = 0; kf < 2; ++kf)
                sacc = __builtin_amdgcn_mfma_f32_16x16x32_f16(qf[t][mf][kf], kfr[nf2][kf], sacc, 0, 0, 0);
              #pragma unroll
              for (int r = 0; r < 4; ++r) {
                int i = i0t[t] + mf * 16 + lg * 4 + r;
                int j = js + nf2 * 16 + lr;
                float v = (j <= i) ? fmaxf(sacc[r], 0.f) : 0.f;
                sw[(mf * 16 + lg * 4 + r) * 40 + nf2 * 16 + lr] = f2h(v);
              }
            }
          }
          asm volatile("s_waitcnt lgkmcnt(0)" ::: "memory");
          __builtin_amdgcn_sched_barrier(0);
          #pragma unroll
          for (int mf = 0; mf < 2; ++mf) {
            f16x8 sf = *reinterpret_cast<const f16x8*>(&sw[(mf * 16 + lr) * 40 + lg * 8]);
            #pragma unroll
            for (int nf = 0; nf < 4; ++nf)
              oacc[t][mf][nf] = __builtin_amdgcn_mfma_f32_16x16x32_f16(sf, vch[nf], oacc[t][mf][nf], 0, 0, 0);
          }
        }
      }
    }
    if (more) SWRITE(cur ^ 1);
    __syncthreads();
  }

  float hm = head_mask[h];
  float hm3 = hm * hm * hm;
  float* f8 = (float*)sh;
  for (int t = 0; t < 2; ++t) {
    #pragma unroll
    for (int mf = 0; mf < 2; ++mf)
      #pragma unroll
      for (int nf = 0; nf < 4; ++nf)
        #pragma unroll
        for (int r = 0; r < 4; ++r)
          f8[wid * 2048 + (mf * 16 + lg * 4 + r) * 64 + nf * 16 + lr] = oacc[t][mf][nf][r] * hm3;
    __syncthreads();
    for (int idx = tid; idx < 8192; idx += 512) f8[idx] += f8[idx + 8192];
    __syncthreads();
    for (int idx = tid; idx < 4096; idx += 512) f8[idx] += f8[idx + 4096];
    __syncthreads();
    for (int idx = tid; idx < 2048; idx += 512) {
      int rr = idx >> 6;
      f8[idx] = (f8[idx] + f8[idx + 2048]) / (float)(i0t[t] + rr + 1);
    }
    __syncthreads();
    for (int rl = 0; rl < 4; ++rl) {
      int rr = wid * 4 + rl;
      size_t row = ((size_t)b * SEQ + i0t[t] + rr) * EMB;
      int c0 = lane, c1 = lane + 64;
      float x0 = Hst[row + c0];
      float x1 = Hst[row + c1] + f8[rr * 64 + lane];
      float s1 = x0 + x1, s2 = x0 * x0 + x1 * x1;
      #pragma unroll
      for (int off = 1; off < 64; off <<= 1) {
        s1 += __shfl_xor(s1, off);
        s2 += __shfl_xor(s2, off);
      }
      float mu = s1 * (1.f / 128.f);
      float var = s2 * (1.f / 128.f) - mu * mu;
      float rs = rsqrt_acc(var + LN_EPS);
      float y0 = (x0 - mu) * rs * g[c0] + bta[c0];
      float y1 = (x1 - mu) * rs * g[c1] + bta[c1];
      Hst[row + c0] = y0; Hst[row + c1] = y1;
      unsigned short h0, l0, h1, l1; split2(y0, h0, l0); split2(y1, h1, l1);
      HbfOut[row + c0] = h0; HbfOut[hbPl + row + c0] = l0;
      HbfOut[row + c1] = h1; HbfOut[hbPl + row + c1] = l1;
    }
    __syncthreads();
  }
}

// ---------------- fused attention (+LN1), last layer (DHEAD=128), parallel tree epilogue ----------------
__global__ __launch_bounds__(512) void k_attn_fused(
    const unsigned short* __restrict__ q,      // fp16 frag [bh][tb 64][kc 4][512]
    const unsigned short* __restrict__ kbuf,   // fp16 frag [bh][tb 64][kc 4][512]
    const unsigned short* __restrict__ vT,     // fp16 frag [bh][db 8][jc 32][512]
    const float* __restrict__ head_mask,
    float* __restrict__ Hst, unsigned short* __restrict__ HbfOut, size_t hbPl,
    const float* __restrict__ g, const float* __restrict__ bta) {
  constexpr int KF = 4, NFO = 8;
  constexpr int NT = SEQ / 32;
  extern __shared__ char sh[];      // attn: sw [0,20480); epilogue f8 [0,65536)
  int bid = blockIdx.x;
  int xcd = bid & 7, u = bid >> 3;
  int b = xcd * 2 + (u >> 4);
  int pidx = u & 15;
  int tid = threadIdx.x;
  int wid = tid >> 6, lane = tid & 63;
  int h = wid & 3, grp = wid >> 2;
  int lr = lane & 15, lg = lane >> 4;
  unsigned short* sw = (unsigned short*)(sh + wid * 2560);
  const unsigned short* qh = q + (size_t)(b * NHEAD + h) * 131072;
  const unsigned short* kh = kbuf + (size_t)(b * NHEAD + h) * 131072;
  const unsigned short* vh = vT + (size_t)(b * NHEAD + h) * 131072;
  float hm = head_mask[h];
  float hm3 = hm * hm * hm;

  for (int s = 0; s < 2; ++s) {
    int tile = (s == 0) ? pidx : (NT - 1 - pidx);
    int i0 = tile * 32;
    f16x8 qf[2][KF];
    #pragma unroll
    for (int mf = 0; mf < 2; ++mf)
      #pragma unroll
      for (int kf = 0; kf < KF; ++kf)
        qf[mf][kf] = *reinterpret_cast<const f16x8*>(
            qh + ((((i0 >> 4) + mf) * 4 + kf) << 9) + lane * 8);
    f32x4 oacc[2][NFO] = {};
    int jend = i0 + 32;
    for (int j0 = grp * 32; j0 < jend; j0 += 64) {
      f16x8 vch[NFO];
      #pragma unroll
      for (int nf = 0; nf < NFO; ++nf)
        vch[nf] = *reinterpret_cast<const f16x8*>(vh + ((nf * 32 + (j0 >> 5)) << 9) + lane * 8);
      #pragma unroll
      for (int nf2 = 0; nf2 < 2; ++nf2) {
        f16x8 kfr[KF];
        #pragma unroll
        for (int kf = 0; kf < KF; ++kf)
          kfr[kf] = *reinterpret_cast<const f16x8*>(
              kh + ((((j0 >> 4) + nf2) * 4 + kf) << 9) + lane * 8);
        #pragma unroll
        for (int mf = 0; mf < 2; ++mf) {
          f32x4 sacc = {};
          #pragma unroll
          for (int kf = 0; kf < KF; ++kf)
            sacc = __builtin_amdgcn_mfma_f32_16x16x32_f16(qf[mf][kf], kfr[kf], sacc, 0, 0, 0);
          #pragma unroll
          for (int r = 0; r < 4; ++r) {
            int i = i0 + mf * 16 + lg * 4 + r;
            int j = j0 + nf2 * 16 + lr;
            float v = (j <= i) ? fmaxf(sacc[r], 0.f) : 0.f;
            sw[(mf * 16 + lg * 4 + r) * 40 + nf2 * 16 + lr] = f2h(v);
          }
        }
      }
      asm volatile("s_waitcnt lgkmcnt(0)" ::: "memory");
      __builtin_amdgcn_sched_barrier(0);
      #pragma unroll
      for (int mf = 0; mf < 2; ++mf) {
        f16x8 sf = *reinterpret_cast<const f16x8*>(&sw[(mf * 16 + lr) * 40 + lg * 8]);
        #pragma unroll
        for (int nf = 0; nf < NFO; ++nf)
          oacc[mf][nf] = __builtin_amdgcn_mfma_f32_16x16x32_f16(sf, vch[nf], oacc[mf][nf], 0, 0, 0);
      }
    }
    // ---- parallel tree head-sum: f8[4 head-regions][32][128] ----
    float* f8 = (float*)sh;
    __syncthreads();
    if (wid < 4) {
      #pragma unroll
      for (int mf = 0; mf < 2; ++mf)
        #pragma unroll
        for (int nf = 0; nf < NFO; ++nf)
          #pragma unroll
          for (int r = 0; r < 4; ++r)
            f8[(wid & 3) * 4096 + (mf * 16 + lg * 4 + r) * 128 + nf * 16 + lr] = oacc[mf][nf][r] * hm3;
    }
    __syncthreads();
    if (wid >= 4) {
      #pragma unroll
      for (int mf = 0; mf < 2; ++mf)
        #pragma unroll
        for (int nf = 0; nf < NFO; ++nf)
          #pragma unroll
          for (int r = 0; r < 4; ++r)
            f8[(wid & 3) * 4096 + (mf * 16 + lg * 4 + r) * 128 + nf * 16 + lr] += oacc[mf][nf][r] * hm3;
    }
    __syncthreads();
    for (int idx = tid; idx < 8192; idx += 512) f8[idx] += f8[idx + 8192];
    __syncthreads();
    for (int idx = tid; idx < 4096; idx += 512) {
      int rr = idx >> 7;
      f8[idx] = (f8[idx] + f8[idx + 4096]) / (float)(i0 + rr + 1);
    }
    __syncthreads();
    for (int rl = 0; rl < 4; ++rl) {
      int rr = wid * 4 + rl;
      size_t row = ((size_t)b * SEQ + i0 + rr) * EMB;
      int c0 = lane, c1 = lane + 64;
      float x0 = Hst[row + c0] + f8[rr * 128 + c0];
      float x1 = Hst[row + c1] + f8[rr * 128 + c1];
      float s1 = x0 + x1, s2 = x0 * x0 + x1 * x1;
      #pragma unroll
      for (int off = 1; off < 64; off <<= 1) {
        s1 += __shfl_xor(s1, off);
        s2 += __shfl_xor(s2, off);
      }
      float mu = s1 * (1.f / 128.f);
      float var = s2 * (1.f / 128.f) - mu * mu;
      float rs = rsqrt_acc(var + LN_EPS);
      float y0 = (x0 - mu) * rs * g[c0] + bta[c0];
      float y1 = (x1 - mu) * rs * g[c1] + bta[c1];
      Hst[row + c0] = y0; Hst[row + c1] = y1;
      unsigned short h0, l0, h1, l1; split2(y0, h0, l0); split2(y1, h1, l1);
      HbfOut[row + c0] = h0; HbfOut[hbPl + row + c0] = l0;
      HbfOut[row + c1] = h1; HbfOut[hbPl + row + c1] = l1;
    }
    __syncthreads();
  }
}

// ---------------- fused MLP (mlp1 + mlp2 + residual + LN2); mid lives in LDS ----------------
// 16 rows/block, grid 1024, 4 waves. LDS: As[2][16][132] (8448B) | Mid[2][16][516] (33024B);
// yb f32[16][132] aliases As after frags are in registers.
__global__ __launch_bounds__(256) void k_mlpf(
    const unsigned short* __restrict__ A, size_t aPl,      // Hbf2 2-plane
    const unsigned short* __restrict__ W1, size_t w1Pl, const float* __restrict__ b1,
    const unsigned short* __restrict__ W2, size_t w2Pl, const float* __restrict__ b2,
    float* __restrict__ Hst, unsigned short* __restrict__ HbfOut, size_t hbPl,
    unsigned short* __restrict__ Hh,
    const float* __restrict__ g, const float* __restrict__ bta) {
  extern __shared__ unsigned short mlds[];
  unsigned short* As = mlds;              // 2 planes x 16 x 132
  unsigned short* Mid = mlds + 4224;      // 2 planes x 16 x 516
  float* yb = (float*)mlds;               // aliases As (8448 B)
  int tid = threadIdx.x;
  int wid = tid >> 6, lane = tid & 63;
  int lr = lane & 15, lg = lane >> 4;
  int row0g = blockIdx.x * 16;
  {
    const unsigned short* gA = A + (size_t)row0g * 128;
    int e = tid * 8;
    int ro = (e >> 7) * 132 + (e & 127);
    *reinterpret_cast<bf16x8*>(As + ro) = *reinterpret_cast<const bf16x8*>(gA + e);
    *reinterpret_cast<bf16x8*>(As + 2112 + ro) = *reinterpret_cast<const bf16x8*>(gA + aPl + e);
  }
  __syncthreads();
  bf16x8 afh[4], afl[4];
  #pragma unroll
  for (int kf = 0; kf < 4; ++kf) {
    int o = lr * 132 + kf * 32 + lg * 8;
    afh[kf] = *reinterpret_cast<const bf16x8*>(As + o);
    afl[kf] = *reinterpret_cast<const bf16x8*>(As + 2112 + o);
  }
  // ---- mlp1: wave computes n-tiles wid*8 .. wid*8+7, relu, split -> Mid ----
  #pragma unroll
  for (int j = 0; j < 8; ++j) {
    int ntile = wid * 8 + j;
    f32x4 acc = {};
    #pragma unroll
    for (int kf = 0; kf < 4; ++kf) {
      size_t bo = ((size_t)kf * 32 + ntile) * 512 + lane * 8;
      bf16x8 bh = *reinterpret_cast<const bf16x8*>(W1 + bo);
      bf16x8 bl = *reinterpret_cast<const bf16x8*>(W1 + w1Pl + bo);
      acc = __builtin_amdgcn_mfma_f32_16x16x32_bf16(afh[kf], bh, acc, 0, 0, 0);
      acc = __builtin_amdgcn_mfma_f32_16x16x32_bf16(afl[kf], bh, acc, 0, 0, 0);
      acc = __builtin_amdgcn_mfma_f32_16x16x32_bf16(afh[kf], bl, acc, 0, 0, 0);
    }
    int c = ntile * 16 + lr;
    float bv = b1[c];
    #pragma unroll
    for (int r = 0; r < 4; ++r) {
      float v = fmaxf(acc[r] + bv, 0.f);
      unsigned short hi, lo; split2(v, hi, lo);
      int row = lg * 4 + r;
      Mid[row * 516 + c] = hi;
      Mid[8256 + row * 516 + c] = lo;
    }
  }
  __syncthreads();
  // ---- mlp2: wave computes n-tiles wid*2, wid*2+1 over kc=0..15 ----
  f32x4 acc2[2] = {};
  #pragma unroll
  for (int kc = 0; kc < 16; ++kc) {
    int o = lr * 516 + kc * 32 + lg * 8;
    bf16x8 amh = *reinterpret_cast<const bf16x8*>(Mid + o);
    bf16x8 aml = *reinterpret_cast<const bf16x8*>(Mid + 8256 + o);
    #pragma unroll
    for (int j = 0; j < 2; ++j) {
      int ntile = wid * 2 + j;
      size_t bo = ((size_t)kc * 8 + ntile) * 512 + lane * 8;
      bf16x8 bh = *reinterpret_cast<const bf16x8*>(W2 + bo);
      bf16x8 bl = *reinterpret_cast<const bf16x8*>(W2 + w2Pl + bo);
      acc2[j] = __builtin_amdgcn_mfma_f32_16x16x32_bf16(amh, bh, acc2[j], 0, 0, 0);
      acc2[j] = __builtin_amdgcn_mfma_f32_16x16x32_bf16(aml, bh, acc2[j], 0, 0, 0);
      acc2[j] = __builtin_amdgcn_mfma_f32_16x16x32_bf16(amh, bl, acc2[j], 0, 0, 0);
    }
  }
  // ---- residual into yb (aliases dead As region) ----
  #pragma unroll
  for (int j = 0; j < 2; ++j) {
    int c = (wid * 2 + j) * 16 + lr;
    float bv = b2[c];
    #pragma unroll
    for (int r = 0; r < 4; ++r) {
      int row = lg * 4 + r;
      yb[row * 132 + c] = acc2[j][r] + bv + Hst[(size_t)(row0g + row) * EMB + c];
    }
  }
  __syncthreads();
  // ---- LN2: wave owns rows wid*4 .. wid*4+3 ----
  for (int rl = 0; rl < 4; ++rl) {
    int row = wid * 4 + rl;
    size_t gro = (size_t)(row0g + row) * EMB;
    int c0 = lane, c1 = lane + 64;
    float x0 = yb[row * 132 + c0];
    float x1 = yb[row * 132 + c1];
    float s1 = x0 + x1, s2 = x0 * x0 + x1 * x1;
    #pragma unroll
    for (int off = 1; off < 64; off <<= 1) {
      s1 += __shfl_xor(s1, off);
      s2 += __shfl_xor(s2, off);
    }
    float mu = s1 * (1.f / 128.f);
    float var = s2 * (1.f / 128.f) - mu * mu;
    float rs = rsqrt_acc(var + LN_EPS);
    float y0 = (x0 - mu) * rs * g[c0] + bta[c0];
    float y1 = (x1 - mu) * rs * g[c1] + bta[c1];
    Hst[gro + c0] = y0; Hst[gro + c1] = y1;
    unsigned short h0, l0, h1, l1; split2(y0, h0, l0); split2(y1, h1, l1);
    HbfOut[gro + c0] = h0; HbfOut[hbPl + gro + c0] = l0;
    HbfOut[gro + c1] = h1; HbfOut[hbPl + gro + c1] = l1;
    Hh[(size_t)(row0g + row) * 64 + lane] = f2h(y0);
  }
}

// ---------------- readout ----------------
__global__ __launch_bounds__(64) void k_readout(const float* __restrict__ H,
                                                const float* __restrict__ W, const float* __restrict__ b0,
                                                float* __restrict__ out) {
  int idx = blockIdx.x;           // b*512 + p
  int b = idx >> 9, p = idx & 511;
  size_t row = ((size_t)b * SEQ + 2 * p) * EMB;
  int lane = threadIdx.x;
  float acc = H[row + lane] * W[lane] + H[row + 64 + lane] * W[64 + lane];
  #pragma unroll
  for (int off = 1; off < 64; off <<= 1) acc += __shfl_xor(acc, off);
  if (lane == 0) out[idx] = acc + b0[0];
}

extern "C" void kernel_launch(void* const* d_in, const int* in_sizes, int n_in,
                              void* d_out, int out_size, void* d_ws, size_t ws_size,
                              hipStream_t stream) {
  (void)in_sizes; (void)n_in; (void)out_size; (void)ws_size;
  const float* xs        = (const float*)d_in[0];
  const float* ys        = (const float*)d_in[1];
  const float* head_mask = (const float*)d_in[2];
  const float* read_in_W = (const float*)d_in[3];
  const float* read_in_b = (const float*)d_in[4];
  const float* qW        = (const float*)d_in[5];
  const float* vW        = (const float*)d_in[6];
  const float* qW_last   = (const float*)d_in[7];
  const float* kW_last   = (const float*)d_in[8];
  const float* vW_last   = (const float*)d_in[9];
  const float* ln1_g     = (const float*)d_in[10];
  const float* ln1_b     = (const float*)d_in[11];
  const float* ln2_g     = (const float*)d_in[12];
  const float* ln2_b     = (const float*)d_in[13];
  const float* mlp_W1    = (const float*)d_in[14];
  const float* mlp_b1    = (const float*)d_in[15];
  const float* mlp_W2    = (const float*)d_in[16];
  const float* mlp_b2    = (const float*)d_in[17];
  const float* ro_W      = (const float*)d_in[18];
  const float* ro_b      = (const float*)d_in[19];

  const size_t HPL   = (size_t)BS * SEQ * EMB;          // 2M
  const size_t QVWPL = (size_t)11 * 512 * 128;
  const size_t W1PL  = (size_t)12 * 512 * 128;
  const size_t W2PL  = (size_t)12 * 512 * 128;
  const size_t LASTPL= (size_t)1536 * 128;
  const size_t VOFF  = (size_t)BS * NHEAD * 65536;      // v region inside qbuf

  char* ws = (char*)d_ws;
  size_t off = 0;
  auto alloc = [&](size_t bytes) -> void* {
    void* p = ws + off;
    off += (bytes + 255) & ~(size_t)255;
    return p;
  };
  float* H             = (float*)alloc(HPL * 4);                  // 8 MB
  unsigned short* Hbf  = (unsigned short*)alloc(2 * HPL * 2);     // 8 MB
  unsigned short* Hbf2 = (unsigned short*)alloc(2 * HPL * 2);     // 8 MB
  unsigned short* Hh   = (unsigned short*)alloc((size_t)BS * SEQ * 64 * 2);  // 2 MB
  unsigned short* qbuf = (unsigned short*)alloc((size_t)BS * NHEAD * 131072 * 2); // q | v (v7) / q-last
  unsigned short* kmid = (unsigned short*)alloc((size_t)BS * NHEAD * 131072 * 2); // k-last frag
  unsigned short* vTl  = (unsigned short*)alloc((size_t)BS * NHEAD * 131072 * 2); // last v frag
  unsigned short* qvWT = (unsigned short*)alloc(2 * QVWPL * 2);
  unsigned short* W1T  = (unsigned short*)alloc(2 * W1PL * 2);
  unsigned short* W2T  = (unsigned short*)alloc(2 * W2PL * 2);
  unsigned short* lastT= (unsigned short*)alloc(2 * LASTPL * 2);

  { int tot = 11 * 512 * 128; k_prep_qvfrag<<<dim3((tot + 255) / 256), 256, 0, stream>>>(qW, vW, qvWT, QVWPL); }
  { int tot = 12 * 512 * 128; k_prep_fragT<<<dim3((tot + 255) / 256), 256, 0, stream>>>(mlp_W1, W1T, W1PL, 12, 128, 512, 512, 128); }
  { int tot = 12 * 512 * 128; k_prep_fragT<<<dim3((tot + 255) / 256), 256, 0, stream>>>(mlp_W2, W2T, W2PL, 12, 512, 128, 128, 512); }
  { int tot = 1536 * 128; k_prep_lastfrag<<<dim3((tot + 255) / 256), 256, 0, stream>>>(qW_last, kW_last, vW_last, lastT, LASTPL); }

  k_combine_readin<<<dim3(BS * SEQ), 128, 0, stream>>>(xs, ys, read_in_W, read_in_b, H, Hbf, HPL, Hh);

  const int GEMM_LDS = 2 * 64 * 136 * 2;            // 34816 B
  const int MLPF_LDS = (4224 + 16512) * 2;          // 41472 B

  for (int l = 0; l < 11; ++l) {
    k_gemm<3, false><<<dim3(256, 8), 256, GEMM_LDS, stream>>>(
        Hbf, HPL, qvWT + (size_t)l * 65536, QVWPL, nullptr, 512,
        qbuf, qbuf + VOFF, nullptr);
    k_attn_v7<<<dim3(256), 512, 65536, stream>>>(
        qbuf, Hh, qbuf + VOFF, head_mask, H, Hbf2, HPL, ln1_g + l * 128, ln1_b + l * 128);
    k_mlpf<<<dim3(1024), 256, MLPF_LDS, stream>>>(
        Hbf2, HPL, W1T + (size_t)l * 65536, W1PL, mlp_b1 + l * 512,
        W2T + (size_t)l * 65536, W2PL, mlp_b2 + l * 128,
        H, Hbf, HPL, Hh, ln2_g + l * 128, ln2_b + l * 128);
  }
  // last layer
  k_gemm<2, false><<<dim3(256, 24), 256, GEMM_LDS, stream>>>(
      Hbf, HPL, lastT, LASTPL, nullptr, 1536, qbuf, kmid, vTl);
  k_attn_fused<<<dim3(256), 512, 65536, stream>>>(
      qbuf, kmid, vTl, head_mask, H, Hbf2, HPL, ln1_g + 11 * 128, ln1_b + 11 * 128);
  k_mlpf<<<dim3(1024), 256, MLPF_LDS, stream>>>(
      Hbf2, HPL, W1T + (size_t)11 * 65536, W1PL, mlp_b1 + 11 * 512,
      W2T + (size_t)11 * 65536, W2PL, mlp_b2 + 11 * 128,
      H, Hbf, HPL, Hh, ln2_g + 11 * 128, ln2_b + 11 * 128);

  k_readout<<<dim3(8192), 64, 0, stream>>>(H, ro_W, ro_b, (float*)d_out);
}

// Round 13
// 1109.995 us; speedup vs baseline: 1.1606x; 1.0305x over previous
//
#include <hip/hip_runtime.h>

#define BS 16
#define SEQ 1024
#define EMB 128
#define NHEAD 4
#define LN_EPS 1e-5f

typedef __attribute__((ext_vector_type(8))) short bf16x8;
typedef __attribute__((ext_vector_type(8))) _Float16 f16x8;
typedef __attribute__((ext_vector_type(4))) float f32x4;
typedef __attribute__((ext_vector_type(4))) unsigned short u16x4;
typedef __attribute__((ext_vector_type(4))) unsigned int u32x4;

__device__ __forceinline__ unsigned short f2b(float f) {
  union { float f; unsigned u; } v; v.f = f;
  unsigned r = v.u + 0x7fff + ((v.u >> 16) & 1);
  return (unsigned short)(r >> 16);
}
__device__ __forceinline__ float b2f(unsigned short u) {
  return __uint_as_float((unsigned)u << 16);
}
__device__ __forceinline__ unsigned short f2h(float f) {
  union { _Float16 h; unsigned short u; } v; v.h = (_Float16)f; return v.u;
}
// split x into hi+lo bf16 (3-term Markidis precision: rel err ~2^-17)
__device__ __forceinline__ void split2(float x, unsigned short& hi, unsigned short& lo) {
  unsigned short h = f2b(x);
  float hf = __uint_as_float((unsigned)h << 16);
  hi = h; lo = f2b(x - hf);
}
__device__ __forceinline__ float rsqrt_acc(float v) {
  float r = rsqrtf(v);
  return r * (1.5f - 0.5f * v * r * r);   // one Newton step -> ~f32-exact
}

// ---------------- weight prep: fragment-ordered 2-plane bf16 ----------------
__global__ void k_prep_fragT(const float* __restrict__ in, unsigned short* __restrict__ out,
                             size_t PL, int L, int Kin, int Nin, int N, int K) {
  int idx = blockIdx.x * 256 + threadIdx.x;
  int nblk = (N >> 4) * (K >> 5);
  int total = L * N * K;
  if (idx >= total) return;
  int e = idx & 7;
  int lane = (idx >> 3) & 63;
  int blk = (idx >> 9) % nblk;
  int l = idx / (512 * nblk);
  int nb = blk % (N >> 4), kc = blk / (N >> 4);
  int n = nb * 16 + (lane & 15);
  int k = kc * 32 + (lane >> 4) * 8 + e;
  float v = (k < Kin && n < Nin) ? in[(size_t)l * Kin * Nin + (size_t)k * Nin + n] : 0.f;
  unsigned short hi, lo; split2(v, hi, lo);
  out[idx] = hi; out[PL + idx] = lo;
}

// qvW frag: N=512, K=128; n<256 q side (h=n>>6,d=n&63, d63 zero), else v side
__global__ void k_prep_qvfrag(const float* __restrict__ qW, const float* __restrict__ vW,
                              unsigned short* __restrict__ out, size_t PL) {
  int idx = blockIdx.x * 256 + threadIdx.x;
  int total = 11 * 512 * 128;
  if (idx >= total) return;
  int e = idx & 7;
  int lane = (idx >> 3) & 63;
  int blk = (idx >> 9) & 127;       // kc*32 + nb
  int l = idx >> 16;
  int nb = blk & 31, kc = blk >> 5;
  int n = nb * 16 + (lane & 15);
  int k = kc * 32 + (lane >> 4) * 8 + e;
  float v = 0.f;
  if (n < 256) {
    int hh = n >> 6, d = n & 63;
    if (d < 63 && k >= 64 && k < 127) v = qW[(size_t)l * 63 * 252 + (size_t)(k - 64) * 252 + hh * 63 + d];
  } else {
    int n2 = n - 256, hh = n2 >> 6, d = n2 & 63;
    if (d < 63 && k < 63) v = vW[(size_t)l * 63 * 252 + (size_t)k * 252 + hh * 63 + d];
  }
  unsigned short hi, lo; split2(v, hi, lo);
  out[idx] = hi; out[PL + idx] = lo;
}

// last-layer qkv frag: N=1536, K=128
__global__ void k_prep_lastfrag(const float* __restrict__ qW, const float* __restrict__ kW,
                                const float* __restrict__ vW,
                                unsigned short* __restrict__ out, size_t PL) {
  int idx = blockIdx.x * 256 + threadIdx.x;
  int total = 1536 * 128;
  if (idx >= total) return;
  int e = idx & 7;
  int lane = (idx >> 3) & 63;
  int blk = idx >> 9;               // kc*96 + nb
  int nb = blk % 96, kc = blk / 96;
  int n = nb * 16 + (lane & 15);
  int k = kc * 32 + (lane >> 4) * 8 + e;
  int tsel = n >> 9, n2 = n & 511;
  const float* W = tsel == 0 ? qW : (tsel == 1 ? kW : vW);
  float v = W[(size_t)k * 512 + n2];
  unsigned short hi, lo; split2(v, hi, lo);
  out[idx] = hi; out[PL + idx] = lo;
}

// ---------------- combine + read_in (2-plane bf16 state only) ----------------
__global__ void k_combine_readin(const float* __restrict__ xs, const float* __restrict__ ys,
                                 const float* __restrict__ W, const float* __restrict__ bias,
                                 unsigned short* __restrict__ Hbf, size_t hbPl,
                                 unsigned short* __restrict__ Hh) {
  int blk = blockIdx.x;            // b*1024 + t
  int b = blk >> 10, t = blk & 1023, p = t >> 1;
  __shared__ float zs[64];
  int tid = threadIdx.x;           // 128
  if (tid < 64) {
    float v;
    if (tid < 63) v = xs[((size_t)b * 512 + p) * 63 + tid];
    else v = (t & 1) ? ys[(size_t)b * 512 + p] : 0.f;
    zs[tid] = v;
  }
  __syncthreads();
  float acc = bias[tid];
  #pragma unroll 8
  for (int d = 0; d < 64; ++d) acc += zs[d] * W[d * 128 + tid];
  size_t o = (size_t)blk * 128 + tid;
  unsigned short hi, lo; split2(acc, hi, lo);
  Hbf[o] = hi; Hbf[hbPl + o] = lo;
  if (tid < 64) Hh[(size_t)blk * 64 + tid] = f2h(acc);  // fp16 K image (dims 0..63)
}

// ---------------- split-precision MFMA GEMM: A LDS-staged, B fragment-ordered ----------------
// MODE 2: last qkv frag fp16; MODE 3: qv frag fp16
template<int MODE, bool RELU>
__global__ __launch_bounds__(256) void k_gemm(
    const unsigned short* __restrict__ A, size_t aPl,
    const unsigned short* __restrict__ BT, size_t bPl, const float* __restrict__ bias,
    int N,
    unsigned short* __restrict__ out0,
    unsigned short* __restrict__ out1,
    unsigned short* __restrict__ out2) {
  extern __shared__ unsigned short lds[];   // A 2 planes [64][136] = 34816 B; tile reuse
  int tid = threadIdx.x;
  int wid = tid >> 6, lane = tid & 63;
  int lr = lane & 15, lg = lane >> 4;
  int row0g = blockIdx.x * 64;
  int n0 = blockIdx.y * 64;
  unsigned short* Ah = lds;
  unsigned short* Al = Ah + 64 * 136;
  {
    const unsigned short* gA = A + (size_t)row0g * 128;
    const unsigned short* srcs[2] = { gA, gA + aPl };
    unsigned short* dsts[2] = { Ah, Al };
    #pragma unroll
    for (int p = 0; p < 2; ++p)
      #pragma unroll
      for (int it = 0; it < 4; ++it) {
        int e = it * 2048 + tid * 8;
        bf16x8 v = *reinterpret_cast<const bf16x8*>(srcs[p] + e);
        *reinterpret_cast<bf16x8*>(dsts[p] + (e >> 7) * 136 + (e & 127)) = v;
      }
  }
  __syncthreads();
  bf16x8 afh[4], afl[4];
  #pragma unroll
  for (int kf = 0; kf < 4; ++kf) {
    int o = (wid * 16 + lr) * 136 + kf * 32 + lg * 8;
    afh[kf] = *reinterpret_cast<const bf16x8*>(Ah + o);
    afl[kf] = *reinterpret_cast<const bf16x8*>(Al + o);
  }
  f32x4 acc[4] = {};
  int nhw = N >> 4;
  #pragma unroll
  for (int nf = 0; nf < 4; ++nf) {
    #pragma unroll
    for (int kf = 0; kf < 4; ++kf) {
      size_t bo = ((size_t)kf * nhw + (n0 >> 4) + nf) * 512 + lane * 8;
      bf16x8 bh = *reinterpret_cast<const bf16x8*>(BT + bo);
      bf16x8 bl = *reinterpret_cast<const bf16x8*>(BT + bPl + bo);
      acc[nf] = __builtin_amdgcn_mfma_f32_16x16x32_bf16(afh[kf], bh, acc[nf], 0, 0, 0);
      acc[nf] = __builtin_amdgcn_mfma_f32_16x16x32_bf16(afl[kf], bh, acc[nf], 0, 0, 0);
      acc[nf] = __builtin_amdgcn_mfma_f32_16x16x32_bf16(afh[kf], bl, acc[nf], 0, 0, 0);
    }
  }
  __syncthreads();   // done with staged A; reuse lds for the output tile
  #pragma unroll
  for (int nf = 0; nf < 4; ++nf) {
    int c = n0 + nf * 16 + lr;
    float bv = bias ? bias[c] : 0.f;
    #pragma unroll
    for (int r = 0; r < 4; ++r) {
      float v = acc[nf][r] + bv;
      if (RELU) v = fmaxf(v, 0.f);
      int rL = wid * 16 + lg * 4 + r, cL = nf * 16 + lr;
      ((unsigned short(*)[66])lds)[rL][cL] = f2h(v);
    }
  }
  __syncthreads();
  int u = tid * 2;
  int lane2 = u >> 3, e0 = u & 7;
  if (MODE == 2) {
    unsigned short (*t16)[66] = (unsigned short(*)[66])lds;
    int b = row0g >> 10, t0 = row0g & 1023;
    int tsel = n0 >> 9, c2b = n0 & 511, hh = c2b >> 7, dbase = c2b & 127;
    size_t bh = (size_t)b * NHEAD + hh;
    if (tsel < 2) {
      unsigned short* base = tsel ? out1 : out0;
      int tb0 = t0 >> 4, kc0 = dbase >> 5;
      #pragma unroll
      for (int fb = 0; fb < 8; ++fb) {
        int tbl = fb >> 1, kcl = fb & 1;
        int t_l = tbl * 16 + (lane2 & 15);
        int c_l = kcl * 32 + ((lane2 >> 4) << 3) + e0;
        size_t dst = ((bh * 64 + tb0 + tbl) * 4 + kc0 + kcl) * 512 + lane2 * 8 + e0;
        base[dst] = t16[t_l][c_l];
        base[dst + 1] = t16[t_l][c_l + 1];
      }
    } else {
      int db0 = dbase >> 4, jc0 = t0 >> 5;
      #pragma unroll
      for (int fb = 0; fb < 8; ++fb) {
        int dbl = fb >> 1, jcl = fb & 1;
        int c_l = dbl * 16 + (lane2 & 15);
        int t_l = jcl * 32 + ((lane2 >> 4) << 3) + e0;
        size_t dst = ((bh * 8 + db0 + dbl) * 32 + jc0 + jcl) * 512 + lane2 * 8 + e0;
        out2[dst] = t16[t_l][c_l];
        out2[dst + 1] = t16[t_l + 1][c_l];
      }
    }
  } else {  // MODE 3
    unsigned short (*t16)[66] = (unsigned short(*)[66])lds;
    int b = row0g >> 10, t0 = row0g & 1023;
    if (n0 < 256) {
      size_t bh = (size_t)b * NHEAD + (n0 >> 6);
      int tb0 = t0 >> 4;
      #pragma unroll
      for (int fb = 0; fb < 8; ++fb) {
        int tbl = fb >> 1, kcl = fb & 1;
        int t_l = tbl * 16 + (lane2 & 15);
        int c_l = kcl * 32 + ((lane2 >> 4) << 3) + e0;
        size_t dst = ((bh * 64 + tb0 + tbl) * 2 + kcl) * 512 + lane2 * 8 + e0;
        out0[dst] = t16[t_l][c_l];
        out0[dst + 1] = t16[t_l][c_l + 1];
      }
    } else {
      size_t bh = (size_t)b * NHEAD + ((n0 - 256) >> 6);
      int jc0 = t0 >> 5;
      #pragma unroll
      for (int fb = 0; fb < 8; ++fb) {
        int dbl = fb >> 1, jcl = fb & 1;
        int c_l = dbl * 16 + (lane2 & 15);
        int t_l = jcl * 32 + ((lane2 >> 4) << 3) + e0;
        size_t dst = ((bh * 4 + dbl) * 32 + jc0 + jcl) * 512 + lane2 * 8 + e0;
        out1[dst] = t16[t_l][c_l];
        out1[dst + 1] = t16[t_l + 1][c_l];
      }
    }
  }
}

// ---------------- attention v7 (layers 0-10, D=64); 2-plane state in/out ----------------
__global__ __launch_bounds__(512) void k_attn_v7(
    const unsigned short* __restrict__ q,      // fp16 frag [bh][tb 64][kc 2][512]
    const unsigned short* __restrict__ Hh,     // fp16 [b][t][64]
    const unsigned short* __restrict__ vT,     // fp16 frag [bh][db 4][jc 32][512]
    const float* __restrict__ head_mask,
    const unsigned short* __restrict__ HbfIn, unsigned short* __restrict__ HbfOut, size_t hbPl,
    const float* __restrict__ g, const float* __restrict__ bta) {
  extern __shared__ char sh[];
  int bid = blockIdx.x;
  int xcd = bid & 7, u = bid >> 3;
  int b = xcd * 2 + (u >> 4);
  int pidx = u & 15;
  int tid = threadIdx.x;
  int wid = tid >> 6, lane = tid & 63;
  int h = wid & 3, grp = wid >> 2;
  int lr = lane & 15, lg = lane >> 4;
  int i0t[2] = { pidx * 32, (31 - pidx) * 32 };
  int NSS = (33 - pidx) >> 1;

  const char* gK = (const char*)(Hh + (size_t)b * SEQ * 64);
  char* KB = sh;
  unsigned short* sw = (unsigned short*)(sh + 16384 + wid * 2560);

  const unsigned short* qh = q + (size_t)(b * NHEAD + h) * 65536;
  const unsigned short* vh = vT + (size_t)(b * NHEAD + h) * 65536;

  f16x8 qf[2][2][2];
  #pragma unroll
  for (int t = 0; t < 2; ++t)
    #pragma unroll
    for (int mf = 0; mf < 2; ++mf)
      #pragma unroll
      for (int kf = 0; kf < 2; ++kf)
        qf[t][mf][kf] = *reinterpret_cast<const f16x8*>(
            qh + ((((i0t[t] >> 4) + mf) * 2 + kf) << 9) + lane * 8);
  f32x4 oacc[2][2][4] = {};

  u32x4 sreg;
  auto SLOAD = [&](int ss) {
    sreg = *reinterpret_cast<const u32x4*>(gK + (size_t)ss * 8192 + tid * 16);
  };
  auto SWRITE = [&](int buf) {
    int row = tid >> 3, colb = (tid & 7) * 16;
    *reinterpret_cast<u32x4*>(KB + buf * 8192 + row * 128 + (colb ^ ((row & 7) << 4))) = sreg;
  };

  SLOAD(0); SWRITE(0);
  __syncthreads();

  for (int ss = 0; ss < NSS; ++ss) {
    int cur = ss & 1;
    bool more = (ss + 1 < NSS);
    if (more) SLOAD(ss + 1);
    int js = ss * 64 + grp * 32;
    if (js < i0t[1] + 32) {
      f16x8 vch[4];
      #pragma unroll
      for (int nf = 0; nf < 4; ++nf)
        vch[nf] = *reinterpret_cast<const f16x8*>(vh + ((nf * 32 + (js >> 5)) << 9) + lane * 8);
      f16x8 kfr[2][2];
      #pragma unroll
      for (int nf2 = 0; nf2 < 2; ++nf2)
        #pragma unroll
        for (int kf = 0; kf < 2; ++kf) {
          int row = grp * 32 + nf2 * 16 + lr;
          int colb = kf * 64 + lg * 16;
          kfr[nf2][kf] = *reinterpret_cast<const f16x8*>(
              KB + cur * 8192 + row * 128 + (colb ^ ((row & 7) << 4)));
        }
      #pragma unroll
      for (int t = 0; t < 2; ++t) {
        if (js < i0t[t] + 32) {
          #pragma unroll
          for (int nf2 = 0; nf2 < 2; ++nf2) {
            #pragma unroll
            for (int mf = 0; mf < 2; ++mf) {
              f32x4 sacc = {};
              #pragma unroll
              for (int kf = 0; kf < 2; ++kf)
                sacc = __builtin_amdgcn_mfma_f32_16x16x32_f16(qf[t][mf][kf], kfr[nf2][kf], sacc, 0, 0, 0);
              #pragma unroll
              for (int r = 0; r < 4; ++r) {
                int i = i0t[t] + mf * 16 + lg * 4 + r;
                int j = js + nf2 * 16 + lr;
                float v = (j <= i) ? fmaxf(sacc[r], 0.f) : 0.f;
                sw[(mf * 16 + lg * 4 + r) * 40 + nf2 * 16 + lr] = f2h(v);
              }
            }
          }
          asm volatile("s_waitcnt lgkmcnt(0)" ::: "memory");
          __builtin_amdgcn_sched_barrier(0);
          #pragma unroll
          for (int mf = 0; mf < 2; ++mf) {
            f16x8 sf = *reinterpret_cast<const f16x8*>(&sw[(mf * 16 + lr) * 40 + lg * 8]);
            #pragma unroll
            for (int nf = 0; nf < 4; ++nf)
              oacc[t][mf][nf] = __builtin_amdgcn_mfma_f32_16x16x32_f16(sf, vch[nf], oacc[t][mf][nf], 0, 0, 0);
          }
        }
      }
    }
    if (more) SWRITE(cur ^ 1);
    __syncthreads();
  }

  float hm = head_mask[h];
  float hm3 = hm * hm * hm;
  float* f8 = (float*)sh;
  for (int t = 0; t < 2; ++t) {
    #pragma unroll
    for (int mf = 0; mf < 2; ++mf)
      #pragma unroll
      for (int nf = 0; nf < 4; ++nf)
        #pragma unroll
        for (int r = 0; r < 4; ++r)
          f8[wid * 2048 + (mf * 16 + lg * 4 + r) * 64 + nf * 16 + lr] = oacc[t][mf][nf][r] * hm3;
    __syncthreads();
    for (int idx = tid; idx < 8192; idx += 512) f8[idx] += f8[idx + 8192];
    __syncthreads();
    for (int idx = tid; idx < 4096; idx += 512) f8[idx] += f8[idx + 4096];
    __syncthreads();
    for (int idx = tid; idx < 2048; idx += 512) {
      int rr = idx >> 6;
      f8[idx] = (f8[idx] + f8[idx + 2048]) / (float)(i0t[t] + rr + 1);
    }
    __syncthreads();
    for (int rl = 0; rl < 4; ++rl) {
      int rr = wid * 4 + rl;
      size_t row = ((size_t)b * SEQ + i0t[t] + rr) * EMB;
      int c0 = lane, c1 = lane + 64;
      float x0 = b2f(HbfIn[row + c0]) + b2f(HbfIn[hbPl + row + c0]);
      float x1 = b2f(HbfIn[row + c1]) + b2f(HbfIn[hbPl + row + c1]) + f8[rr * 64 + lane];
      float s1 = x0 + x1, s2 = x0 * x0 + x1 * x1;
      #pragma unroll
      for (int off = 1; off < 64; off <<= 1) {
        s1 += __shfl_xor(s1, off);
        s2 += __shfl_xor(s2, off);
      }
      float mu = s1 * (1.f / 128.f);
      float var = s2 * (1.f / 128.f) - mu * mu;
      float rs = rsqrt_acc(var + LN_EPS);
      float y0 = (x0 - mu) * rs * g[c0] + bta[c0];
      float y1 = (x1 - mu) * rs * g[c1] + bta[c1];
      unsigned short h0, l0, h1, l1; split2(y0, h0, l0); split2(y1, h1, l1);
      HbfOut[row + c0] = h0; HbfOut[hbPl + row + c0] = l0;
      HbfOut[row + c1] = h1; HbfOut[hbPl + row + c1] = l1;
    }
    __syncthreads();
  }
}

// ---------------- fused attention (+LN1), last layer (DHEAD=128); 2-plane state ----------------
__global__ __launch_bounds__(512) void k_attn_fused(
    const unsigned short* __restrict__ q,      // fp16 frag [bh][tb 64][kc 4][512]
    const unsigned short* __restrict__ kbuf,   // fp16 frag [bh][tb 64][kc 4][512]
    const unsigned short* __restrict__ vT,     // fp16 frag [bh][db 8][jc 32][512]
    const float* __restrict__ head_mask,
    const unsigned short* __restrict__ HbfIn, unsigned short* __restrict__ HbfOut, size_t hbPl,
    const float* __restrict__ g, const float* __restrict__ bta) {
  constexpr int KF = 4, NFO = 8;
  constexpr int NT = SEQ / 32;
  extern __shared__ char sh[];      // attn: sw [0,20480); epilogue f8 [0,65536)
  int bid = blockIdx.x;
  int xcd = bid & 7, u = bid >> 3;
  int b = xcd * 2 + (u >> 4);
  int pidx = u & 15;
  int tid = threadIdx.x;
  int wid = tid >> 6, lane = tid & 63;
  int h = wid & 3, grp = wid >> 2;
  int lr = lane & 15, lg = lane >> 4;
  unsigned short* sw = (unsigned short*)(sh + wid * 2560);
  const unsigned short* qh = q + (size_t)(b * NHEAD + h) * 131072;
  const unsigned short* kh = kbuf + (size_t)(b * NHEAD + h) * 131072;
  const unsigned short* vh = vT + (size_t)(b * NHEAD + h) * 131072;
  float hm = head_mask[h];
  float hm3 = hm * hm * hm;

  for (int s = 0; s < 2; ++s) {
    int tile = (s == 0) ? pidx : (NT - 1 - pidx);
    int i0 = tile * 32;
    f16x8 qf[2][KF];
    #pragma unroll
    for (int mf = 0; mf < 2; ++mf)
      #pragma unroll
      for (int kf = 0; kf < KF; ++kf)
        qf[mf][kf] = *reinterpret_cast<const f16x8*>(
            qh + ((((i0 >> 4) + mf) * 4 + kf) << 9) + lane * 8);
    f32x4 oacc[2][NFO] = {};
    int jend = i0 + 32;
    for (int j0 = grp * 32; j0 < jend; j0 += 64) {
      f16x8 vch[NFO];
      #pragma unroll
      for (int nf = 0; nf < NFO; ++nf)
        vch[nf] = *reinterpret_cast<const f16x8*>(vh + ((nf * 32 + (j0 >> 5)) << 9) + lane * 8);
      #pragma unroll
      for (int nf2 = 0; nf2 < 2; ++nf2) {
        f16x8 kfr[KF];
        #pragma unroll
        for (int kf = 0; kf < KF; ++kf)
          kfr[kf] = *reinterpret_cast<const f16x8*>(
              kh + ((((j0 >> 4) + nf2) * 4 + kf) << 9) + lane * 8);
        #pragma unroll
        for (int mf = 0; mf < 2; ++mf) {
          f32x4 sacc = {};
          #pragma unroll
          for (int kf = 0; kf < KF; ++kf)
            sacc = __builtin_amdgcn_mfma_f32_16x16x32_f16(qf[mf][kf], kfr[kf], sacc, 0, 0, 0);
          #pragma unroll
          for (int r = 0; r < 4; ++r) {
            int i = i0 + mf * 16 + lg * 4 + r;
            int j = j0 + nf2 * 16 + lr;
            float v = (j <= i) ? fmaxf(sacc[r], 0.f) : 0.f;
            sw[(mf * 16 + lg * 4 + r) * 40 + nf2 * 16 + lr] = f2h(v);
          }
        }
      }
      asm volatile("s_waitcnt lgkmcnt(0)" ::: "memory");
      __builtin_amdgcn_sched_barrier(0);
      #pragma unroll
      for (int mf = 0; mf < 2; ++mf) {
        f16x8 sf = *reinterpret_cast<const f16x8*>(&sw[(mf * 16 + lr) * 40 + lg * 8]);
        #pragma unroll
        for (int nf = 0; nf < NFO; ++nf)
          oacc[mf][nf] = __builtin_amdgcn_mfma_f32_16x16x32_f16(sf, vch[nf], oacc[mf][nf], 0, 0, 0);
      }
    }
    // ---- parallel tree head-sum: f8[4 head-regions][32][128] ----
    float* f8 = (float*)sh;
    __syncthreads();
    if (wid < 4) {
      #pragma unroll
      for (int mf = 0; mf < 2; ++mf)
        #pragma unroll
        for (int nf = 0; nf < NFO; ++nf)
          #pragma unroll
          for (int r = 0; r < 4; ++r)
            f8[(wid & 3) * 4096 + (mf * 16 + lg * 4 + r) * 128 + nf * 16 + lr] = oacc[mf][nf][r] * hm3;
    }
    __syncthreads();
    if (wid >= 4) {
      #pragma unroll
      for (int mf = 0; mf < 2; ++mf)
        #pragma unroll
        for (int nf = 0; nf < NFO; ++nf)
          #pragma unroll
          for (int r = 0; r < 4; ++r)
            f8[(wid & 3) * 4096 + (mf * 16 + lg * 4 + r) * 128 + nf * 16 + lr] += oacc[mf][nf][r] * hm3;
    }
    __syncthreads();
    for (int idx = tid; idx < 8192; idx += 512) f8[idx] += f8[idx + 8192];
    __syncthreads();
    for (int idx = tid; idx < 4096; idx += 512) {
      int rr = idx >> 7;
      f8[idx] = (f8[idx] + f8[idx + 4096]) / (float)(i0 + rr + 1);
    }
    __syncthreads();
    for (int rl = 0; rl < 4; ++rl) {
      int rr = wid * 4 + rl;
      size_t row = ((size_t)b * SEQ + i0 + rr) * EMB;
      int c0 = lane, c1 = lane + 64;
      float x0 = b2f(HbfIn[row + c0]) + b2f(HbfIn[hbPl + row + c0]) + f8[rr * 128 + c0];
      float x1 = b2f(HbfIn[row + c1]) + b2f(HbfIn[hbPl + row + c1]) + f8[rr * 128 + c1];
      float s1 = x0 + x1, s2 = x0 * x0 + x1 * x1;
      #pragma unroll
      for (int off = 1; off < 64; off <<= 1) {
        s1 += __shfl_xor(s1, off);
        s2 += __shfl_xor(s2, off);
      }
      float mu = s1 * (1.f / 128.f);
      float var = s2 * (1.f / 128.f) - mu * mu;
      float rs = rsqrt_acc(var + LN_EPS);
      float y0 = (x0 - mu) * rs * g[c0] + bta[c0];
      float y1 = (x1 - mu) * rs * g[c1] + bta[c1];
      unsigned short h0, l0, h1, l1; split2(y0, h0, l0); split2(y1, h1, l1);
      HbfOut[row + c0] = h0; HbfOut[hbPl + row + c0] = l0;
      HbfOut[row + c1] = h1; HbfOut[hbPl + row + c1] = l1;
    }
    __syncthreads();
  }
}

// ---------------- fused MLP (mlp1 + mlp2 + residual + LN2); residual from LDS A tile ----------------
// 16 rows/block, grid 1024, 4 waves. LDS: As[2][16][132] | Mid[2][16][516]; yb aliases As? No:
// As needed for residual -> yb goes after Mid (small extra 8448B? keep separate region).
template<bool LAST>
__global__ __launch_bounds__(256) void k_mlpf(
    const unsigned short* __restrict__ A, size_t aPl,      // Hbf2 2-plane (post-LN1 y)
    const unsigned short* __restrict__ W1, size_t w1Pl, const float* __restrict__ b1,
    const unsigned short* __restrict__ W2, size_t w2Pl, const float* __restrict__ b2,
    unsigned short* __restrict__ HbfOut, size_t hbPl,
    unsigned short* __restrict__ Hh, float* __restrict__ Hst,
    const float* __restrict__ g, const float* __restrict__ bta) {
  extern __shared__ unsigned short mlds[];
  unsigned short* As = mlds;              // 2 planes x 16 x 132 (4224 u16)
  unsigned short* Mid = mlds + 4224;      // 2 planes x 16 x 516 (16512 u16)
  float* yb = (float*)(mlds + 4224 + 16512);  // f32 [16][132] (8448 B)
  int tid = threadIdx.x;
  int wid = tid >> 6, lane = tid & 63;
  int lr = lane & 15, lg = lane >> 4;
  int row0g = blockIdx.x * 16;
  {
    const unsigned short* gA = A + (size_t)row0g * 128;
    int e = tid * 8;
    int ro = (e >> 7) * 132 + (e & 127);
    *reinterpret_cast<bf16x8*>(As + ro) = *reinterpret_cast<const bf16x8*>(gA + e);
    *reinterpret_cast<bf16x8*>(As + 2112 + ro) = *reinterpret_cast<const bf16x8*>(gA + aPl + e);
  }
  __syncthreads();
  bf16x8 afh[4], afl[4];
  #pragma unroll
  for (int kf = 0; kf < 4; ++kf) {
    int o = lr * 132 + kf * 32 + lg * 8;
    afh[kf] = *reinterpret_cast<const bf16x8*>(As + o);
    afl[kf] = *reinterpret_cast<const bf16x8*>(As + 2112 + o);
  }
  // ---- mlp1: wave computes n-tiles wid*8 .. wid*8+7, relu, split -> Mid ----
  #pragma unroll
  for (int j = 0; j < 8; ++j) {
    int ntile = wid * 8 + j;
    f32x4 acc = {};
    #pragma unroll
    for (int kf = 0; kf < 4; ++kf) {
      size_t bo = ((size_t)kf * 32 + ntile) * 512 + lane * 8;
      bf16x8 bh = *reinterpret_cast<const bf16x8*>(W1 + bo);
      bf16x8 bl = *reinterpret_cast<const bf16x8*>(W1 + w1Pl + bo);
      acc = __builtin_amdgcn_mfma_f32_16x16x32_bf16(afh[kf], bh, acc, 0, 0, 0);
      acc = __builtin_amdgcn_mfma_f32_16x16x32_bf16(afl[kf], bh, acc, 0, 0, 0);
      acc = __builtin_amdgcn_mfma_f32_16x16x32_bf16(afh[kf], bl, acc, 0, 0, 0);
    }
    int c = ntile * 16 + lr;
    float bv = b1[c];
    #pragma unroll
    for (int r = 0; r < 4; ++r) {
      float v = fmaxf(acc[r] + bv, 0.f);
      unsigned short hi, lo; split2(v, hi, lo);
      int row = lg * 4 + r;
      Mid[row * 516 + c] = hi;
      Mid[8256 + row * 516 + c] = lo;
    }
  }
  __syncthreads();
  // ---- mlp2: wave computes n-tiles wid*2, wid*2+1 over kc=0..15 ----
  f32x4 acc2[2] = {};
  #pragma unroll
  for (int kc = 0; kc < 16; ++kc) {
    int o = lr * 516 + kc * 32 + lg * 8;
    bf16x8 amh = *reinterpret_cast<const bf16x8*>(Mid + o);
    bf16x8 aml = *reinterpret_cast<const bf16x8*>(Mid + 8256 + o);
    #pragma unroll
    for (int j = 0; j < 2; ++j) {
      int ntile = wid * 2 + j;
      size_t bo = ((size_t)kc * 8 + ntile) * 512 + lane * 8;
      bf16x8 bh = *reinterpret_cast<const bf16x8*>(W2 + bo);
      bf16x8 bl = *reinterpret_cast<const bf16x8*>(W2 + w2Pl + bo);
      acc2[j] = __builtin_amdgcn_mfma_f32_16x16x32_bf16(amh, bh, acc2[j], 0, 0, 0);
      acc2[j] = __builtin_amdgcn_mfma_f32_16x16x32_bf16(aml, bh, acc2[j], 0, 0, 0);
      acc2[j] = __builtin_amdgcn_mfma_f32_16x16x32_bf16(amh, bl, acc2[j], 0, 0, 0);
    }
  }
  // ---- residual from As reconstruction into yb ----
  #pragma unroll
  for (int j = 0; j < 2; ++j) {
    int c = (wid * 2 + j) * 16 + lr;
    float bv = b2[c];
    #pragma unroll
    for (int r = 0; r < 4; ++r) {
      int row = lg * 4 + r;
      float yres = b2f(As[row * 132 + c]) + b2f(As[2112 + row * 132 + c]);
      yb[row * 132 + c] = acc2[j][r] + bv + yres;
    }
  }
  __syncthreads();
  // ---- LN2: wave owns rows wid*4 .. wid*4+3 ----
  for (int rl = 0; rl < 4; ++rl) {
    int row = wid * 4 + rl;
    size_t gro = (size_t)(row0g + row) * EMB;
    int c0 = lane, c1 = lane + 64;
    float x0 = yb[row * 132 + c0];
    float x1 = yb[row * 132 + c1];
    float s1 = x0 + x1, s2 = x0 * x0 + x1 * x1;
    #pragma unroll
    for (int off = 1; off < 64; off <<= 1) {
      s1 += __shfl_xor(s1, off);
      s2 += __shfl_xor(s2, off);
    }
    float mu = s1 * (1.f / 128.f);
    float var = s2 * (1.f / 128.f) - mu * mu;
    float rs = rsqrt_acc(var + LN_EPS);
    float y0 = (x0 - mu) * rs * g[c0] + bta[c0];
    float y1 = (x1 - mu) * rs * g[c1] + bta[c1];
    unsigned short h0, l0, h1, l1; split2(y0, h0, l0); split2(y1, h1, l1);
    HbfOut[gro + c0] = h0; HbfOut[hbPl + gro + c0] = l0;
    HbfOut[gro + c1] = h1; HbfOut[hbPl + gro + c1] = l1;
    Hh[(size_t)(row0g + row) * 64 + lane] = f2h(y0);
    if (LAST) { Hst[gro + c0] = y0; Hst[gro + c1] = y1; }
  }
}

// ---------------- readout ----------------
__global__ __launch_bounds__(64) void k_readout(const float* __restrict__ H,
                                                const float* __restrict__ W, const float* __restrict__ b0,
                                                float* __restrict__ out) {
  int idx = blockIdx.x;           // b*512 + p
  int b = idx >> 9, p = idx & 511;
  size_t row = ((size_t)b * SEQ + 2 * p) * EMB;
  int lane = threadIdx.x;
  float acc = H[row + lane] * W[lane] + H[row + 64 + lane] * W[64 + lane];
  #pragma unroll
  for (int off = 1; off < 64; off <<= 1) acc += __shfl_xor(acc, off);
  if (lane == 0) out[idx] = acc + b0[0];
}

extern "C" void kernel_launch(void* const* d_in, const int* in_sizes, int n_in,
                              void* d_out, int out_size, void* d_ws, size_t ws_size,
                              hipStream_t stream) {
  (void)in_sizes; (void)n_in; (void)out_size; (void)ws_size;
  const float* xs        = (const float*)d_in[0];
  const float* ys        = (const float*)d_in[1];
  const float* head_mask = (const float*)d_in[2];
  const float* read_in_W = (const float*)d_in[3];
  const float* read_in_b = (const float*)d_in[4];
  const float* qW        = (const float*)d_in[5];
  const float* vW        = (const float*)d_in[6];
  const float* qW_last   = (const float*)d_in[7];
  const float* kW_last   = (const float*)d_in[8];
  const float* vW_last   = (const float*)d_in[9];
  const float* ln1_g     = (const float*)d_in[10];
  const float* ln1_b     = (const float*)d_in[11];
  const float* ln2_g     = (const float*)d_in[12];
  const float* ln2_b     = (const float*)d_in[13];
  const float* mlp_W1    = (const float*)d_in[14];
  const float* mlp_b1    = (const float*)d_in[15];
  const float* mlp_W2    = (const float*)d_in[16];
  const float* mlp_b2    = (const float*)d_in[17];
  const float* ro_W      = (const float*)d_in[18];
  const float* ro_b      = (const float*)d_in[19];

  const size_t HPL   = (size_t)BS * SEQ * EMB;          // 2M
  const size_t QVWPL = (size_t)11 * 512 * 128;
  const size_t W1PL  = (size_t)12 * 512 * 128;
  const size_t W2PL  = (size_t)12 * 512 * 128;
  const size_t LASTPL= (size_t)1536 * 128;
  const size_t VOFF  = (size_t)BS * NHEAD * 65536;      // v region inside qbuf

  char* ws = (char*)d_ws;
  size_t off = 0;
  auto alloc = [&](size_t bytes) -> void* {
    void* p = ws + off;
    off += (bytes + 255) & ~(size_t)255;
    return p;
  };
  float* H             = (float*)alloc(HPL * 4);                  // 8 MB (final layer only)
  unsigned short* Hbf  = (unsigned short*)alloc(2 * HPL * 2);     // 8 MB (state)
  unsigned short* Hbf2 = (unsigned short*)alloc(2 * HPL * 2);     // 8 MB (post-LN1)
  unsigned short* Hh   = (unsigned short*)alloc((size_t)BS * SEQ * 64 * 2);  // 2 MB
  unsigned short* qbuf = (unsigned short*)alloc((size_t)BS * NHEAD * 131072 * 2); // q | v (v7) / q-last
  unsigned short* kmid = (unsigned short*)alloc((size_t)BS * NHEAD * 131072 * 2); // k-last frag
  unsigned short* vTl  = (unsigned short*)alloc((size_t)BS * NHEAD * 131072 * 2); // last v frag
  unsigned short* qvWT = (unsigned short*)alloc(2 * QVWPL * 2);
  unsigned short* W1T  = (unsigned short*)alloc(2 * W1PL * 2);
  unsigned short* W2T  = (unsigned short*)alloc(2 * W2PL * 2);
  unsigned short* lastT= (unsigned short*)alloc(2 * LASTPL * 2);

  { int tot = 11 * 512 * 128; k_prep_qvfrag<<<dim3((tot + 255) / 256), 256, 0, stream>>>(qW, vW, qvWT, QVWPL); }
  { int tot = 12 * 512 * 128; k_prep_fragT<<<dim3((tot + 255) / 256), 256, 0, stream>>>(mlp_W1, W1T, W1PL, 12, 128, 512, 512, 128); }
  { int tot = 12 * 512 * 128; k_prep_fragT<<<dim3((tot + 255) / 256), 256, 0, stream>>>(mlp_W2, W2T, W2PL, 12, 512, 128, 128, 512); }
  { int tot = 1536 * 128; k_prep_lastfrag<<<dim3((tot + 255) / 256), 256, 0, stream>>>(qW_last, kW_last, vW_last, lastT, LASTPL); }

  k_combine_readin<<<dim3(BS * SEQ), 128, 0, stream>>>(xs, ys, read_in_W, read_in_b, Hbf, HPL, Hh);

  const int GEMM_LDS = 2 * 64 * 136 * 2;                    // 34816 B
  const int MLPF_LDS = (4224 + 16512) * 2 + 16 * 132 * 4;   // 49920 B

  for (int l = 0; l < 11; ++l) {
    k_gemm<3, false><<<dim3(256, 8), 256, GEMM_LDS, stream>>>(
        Hbf, HPL, qvWT + (size_t)l * 65536, QVWPL, nullptr, 512,
        qbuf, qbuf + VOFF, nullptr);
    k_attn_v7<<<dim3(256), 512, 65536, stream>>>(
        qbuf, Hh, qbuf + VOFF, head_mask, Hbf, Hbf2, HPL, ln1_g + l * 128, ln1_b + l * 128);
    k_mlpf<false><<<dim3(1024), 256, MLPF_LDS, stream>>>(
        Hbf2, HPL, W1T + (size_t)l * 65536, W1PL, mlp_b1 + l * 512,
        W2T + (size_t)l * 65536, W2PL, mlp_b2 + l * 128,
        Hbf, HPL, Hh, nullptr, ln2_g + l * 128, ln2_b + l * 128);
  }
  // last layer
  k_gemm<2, false><<<dim3(256, 24), 256, GEMM_LDS, stream>>>(
      Hbf, HPL, lastT, LASTPL, nullptr, 1536, qbuf, kmid, vTl);
  k_attn_fused<<<dim3(256), 512, 65536, stream>>>(
      qbuf, kmid, vTl, head_mask, Hbf, Hbf2, HPL, ln1_g + 11 * 128, ln1_b + 11 * 128);
  k_mlpf<true><<<dim3(1024), 256, MLPF_LDS, stream>>>(
      Hbf2, HPL, W1T + (size_t)11 * 65536, W1PL, mlp_b1 + 11 * 512,
      W2T + (size_t)11 * 65536, W2PL, mlp_b2 + 11 * 128,
      Hbf, HPL, Hh, H, ln2_g + 11 * 128, ln2_b + 11 * 128);

  k_readout<<<dim3(8192), 64, 0, stream>>>(H, ro_W, ro_b, (float*)d_out);
}

// Round 14
// 925.386 us; speedup vs baseline: 1.3921x; 1.1995x over previous
//
#include <hip/hip_runtime.h>

#define BS 16
#define SEQ 1024
#define EMB 128
#define NHEAD 4
#define LN_EPS 1e-5f

typedef __attribute__((ext_vector_type(8))) short bf16x8;
typedef __attribute__((ext_vector_type(8))) _Float16 f16x8;
typedef __attribute__((ext_vector_type(4))) float f32x4;
typedef __attribute__((ext_vector_type(4))) unsigned short u16x4;
typedef __attribute__((ext_vector_type(4))) unsigned int u32x4;

__device__ __forceinline__ unsigned short f2b(float f) {
  union { float f; unsigned u; } v; v.f = f;
  unsigned r = v.u + 0x7fff + ((v.u >> 16) & 1);
  return (unsigned short)(r >> 16);
}
__device__ __forceinline__ float b2f(unsigned short u) {
  return __uint_as_float((unsigned)u << 16);
}
__device__ __forceinline__ unsigned short f2h(float f) {
  union { _Float16 h; unsigned short u; } v; v.h = (_Float16)f; return v.u;
}
// split x into hi+lo bf16 (3-term Markidis precision: rel err ~2^-17)
__device__ __forceinline__ void split2(float x, unsigned short& hi, unsigned short& lo) {
  unsigned short h = f2b(x);
  float hf = __uint_as_float((unsigned)h << 16);
  hi = h; lo = f2b(x - hf);
}
__device__ __forceinline__ float rsqrt_acc(float v) {
  float r = rsqrtf(v);
  return r * (1.5f - 0.5f * v * r * r);   // one Newton step -> ~f32-exact
}

// ---------------- weight prep: fragment-ordered 2-plane bf16 ----------------
__global__ void k_prep_fragT(const float* __restrict__ in, unsigned short* __restrict__ out,
                             size_t PL, int L, int Kin, int Nin, int N, int K) {
  int idx = blockIdx.x * 256 + threadIdx.x;
  int nblk = (N >> 4) * (K >> 5);
  int total = L * N * K;
  if (idx >= total) return;
  int e = idx & 7;
  int lane = (idx >> 3) & 63;
  int blk = (idx >> 9) % nblk;
  int l = idx / (512 * nblk);
  int nb = blk % (N >> 4), kc = blk / (N >> 4);
  int n = nb * 16 + (lane & 15);
  int k = kc * 32 + (lane >> 4) * 8 + e;
  float v = (k < Kin && n < Nin) ? in[(size_t)l * Kin * Nin + (size_t)k * Nin + n] : 0.f;
  unsigned short hi, lo; split2(v, hi, lo);
  out[idx] = hi; out[PL + idx] = lo;
}

// qvW frag: N=512, K=128; n<256 q side (h=n>>6,d=n&63, d63 zero), else v side
__global__ void k_prep_qvfrag(const float* __restrict__ qW, const float* __restrict__ vW,
                              unsigned short* __restrict__ out, size_t PL) {
  int idx = blockIdx.x * 256 + threadIdx.x;
  int total = 11 * 512 * 128;
  if (idx >= total) return;
  int e = idx & 7;
  int lane = (idx >> 3) & 63;
  int blk = (idx >> 9) & 127;       // kc*32 + nb
  int l = idx >> 16;
  int nb = blk & 31, kc = blk >> 5;
  int n = nb * 16 + (lane & 15);
  int k = kc * 32 + (lane >> 4) * 8 + e;
  float v = 0.f;
  if (n < 256) {
    int hh = n >> 6, d = n & 63;
    if (d < 63 && k >= 64 && k < 127) v = qW[(size_t)l * 63 * 252 + (size_t)(k - 64) * 252 + hh * 63 + d];
  } else {
    int n2 = n - 256, hh = n2 >> 6, d = n2 & 63;
    if (d < 63 && k < 63) v = vW[(size_t)l * 63 * 252 + (size_t)k * 252 + hh * 63 + d];
  }
  unsigned short hi, lo; split2(v, hi, lo);
  out[idx] = hi; out[PL + idx] = lo;
}

// last-layer qkv frag: N=1536, K=128
__global__ void k_prep_lastfrag(const float* __restrict__ qW, const float* __restrict__ kW,
                                const float* __restrict__ vW,
                                unsigned short* __restrict__ out, size_t PL) {
  int idx = blockIdx.x * 256 + threadIdx.x;
  int total = 1536 * 128;
  if (idx >= total) return;
  int e = idx & 7;
  int lane = (idx >> 3) & 63;
  int blk = idx >> 9;               // kc*96 + nb
  int nb = blk % 96, kc = blk / 96;
  int n = nb * 16 + (lane & 15);
  int k = kc * 32 + (lane >> 4) * 8 + e;
  int tsel = n >> 9, n2 = n & 511;
  const float* W = tsel == 0 ? qW : (tsel == 1 ? kW : vW);
  float v = W[(size_t)k * 512 + n2];
  unsigned short hi, lo; split2(v, hi, lo);
  out[idx] = hi; out[PL + idx] = lo;
}

// ---------------- combine + read_in (2-plane bf16 state only) ----------------
__global__ void k_combine_readin(const float* __restrict__ xs, const float* __restrict__ ys,
                                 const float* __restrict__ W, const float* __restrict__ bias,
                                 unsigned short* __restrict__ Hbf, size_t hbPl,
                                 unsigned short* __restrict__ Hh) {
  int blk = blockIdx.x;            // b*1024 + t
  int b = blk >> 10, t = blk & 1023, p = t >> 1;
  __shared__ float zs[64];
  int tid = threadIdx.x;           // 128
  if (tid < 64) {
    float v;
    if (tid < 63) v = xs[((size_t)b * 512 + p) * 63 + tid];
    else v = (t & 1) ? ys[(size_t)b * 512 + p] : 0.f;
    zs[tid] = v;
  }
  __syncthreads();
  float acc = bias[tid];
  #pragma unroll 8
  for (int d = 0; d < 64; ++d) acc += zs[d] * W[d * 128 + tid];
  size_t o = (size_t)blk * 128 + tid;
  unsigned short hi, lo; split2(acc, hi, lo);
  Hbf[o] = hi; Hbf[hbPl + o] = lo;
  if (tid < 64) Hh[(size_t)blk * 64 + tid] = f2h(acc);  // fp16 K image (dims 0..63)
}

// ---------------- split-precision MFMA GEMM: A LDS-staged, B fragment-ordered ----------------
// MODE 2: last qkv frag fp16; MODE 3: qv frag fp16
template<int MODE, bool RELU>
__global__ __launch_bounds__(256) void k_gemm(
    const unsigned short* __restrict__ A, size_t aPl,
    const unsigned short* __restrict__ BT, size_t bPl, const float* __restrict__ bias,
    int N,
    unsigned short* __restrict__ out0,
    unsigned short* __restrict__ out1,
    unsigned short* __restrict__ out2) {
  extern __shared__ unsigned short lds[];   // A 2 planes [64][136] = 34816 B; tile reuse
  int tid = threadIdx.x;
  int wid = tid >> 6, lane = tid & 63;
  int lr = lane & 15, lg = lane >> 4;
  int row0g = blockIdx.x * 64;
  int n0 = blockIdx.y * 64;
  unsigned short* Ah = lds;
  unsigned short* Al = Ah + 64 * 136;
  {
    const unsigned short* gA = A + (size_t)row0g * 128;
    const unsigned short* srcs[2] = { gA, gA + aPl };
    unsigned short* dsts[2] = { Ah, Al };
    #pragma unroll
    for (int p = 0; p < 2; ++p)
      #pragma unroll
      for (int it = 0; it < 4; ++it) {
        int e = it * 2048 + tid * 8;
        bf16x8 v = *reinterpret_cast<const bf16x8*>(srcs[p] + e);
        *reinterpret_cast<bf16x8*>(dsts[p] + (e >> 7) * 136 + (e & 127)) = v;
      }
  }
  __syncthreads();
  bf16x8 afh[4], afl[4];
  #pragma unroll
  for (int kf = 0; kf < 4; ++kf) {
    int o = (wid * 16 + lr) * 136 + kf * 32 + lg * 8;
    afh[kf] = *reinterpret_cast<const bf16x8*>(Ah + o);
    afl[kf] = *reinterpret_cast<const bf16x8*>(Al + o);
  }
  f32x4 acc[4] = {};
  int nhw = N >> 4;
  #pragma unroll
  for (int nf = 0; nf < 4; ++nf) {
    #pragma unroll
    for (int kf = 0; kf < 4; ++kf) {
      size_t bo = ((size_t)kf * nhw + (n0 >> 4) + nf) * 512 + lane * 8;
      bf16x8 bh = *reinterpret_cast<const bf16x8*>(BT + bo);
      bf16x8 bl = *reinterpret_cast<const bf16x8*>(BT + bPl + bo);
      acc[nf] = __builtin_amdgcn_mfma_f32_16x16x32_bf16(afh[kf], bh, acc[nf], 0, 0, 0);
      acc[nf] = __builtin_amdgcn_mfma_f32_16x16x32_bf16(afl[kf], bh, acc[nf], 0, 0, 0);
      acc[nf] = __builtin_amdgcn_mfma_f32_16x16x32_bf16(afh[kf], bl, acc[nf], 0, 0, 0);
    }
  }
  __syncthreads();   // done with staged A; reuse lds for the output tile
  #pragma unroll
  for (int nf = 0; nf < 4; ++nf) {
    int c = n0 + nf * 16 + lr;
    float bv = bias ? bias[c] : 0.f;
    #pragma unroll
    for (int r = 0; r < 4; ++r) {
      float v = acc[nf][r] + bv;
      if (RELU) v = fmaxf(v, 0.f);
      int rL = wid * 16 + lg * 4 + r, cL = nf * 16 + lr;
      ((unsigned short(*)[66])lds)[rL][cL] = f2h(v);
    }
  }
  __syncthreads();
  int u = tid * 2;
  int lane2 = u >> 3, e0 = u & 7;
  if (MODE == 2) {
    unsigned short (*t16)[66] = (unsigned short(*)[66])lds;
    int b = row0g >> 10, t0 = row0g & 1023;
    int tsel = n0 >> 9, c2b = n0 & 511, hh = c2b >> 7, dbase = c2b & 127;
    size_t bh = (size_t)b * NHEAD + hh;
    if (tsel < 2) {
      unsigned short* base = tsel ? out1 : out0;
      int tb0 = t0 >> 4, kc0 = dbase >> 5;
      #pragma unroll
      for (int fb = 0; fb < 8; ++fb) {
        int tbl = fb >> 1, kcl = fb & 1;
        int t_l = tbl * 16 + (lane2 & 15);
        int c_l = kcl * 32 + ((lane2 >> 4) << 3) + e0;
        size_t dst = ((bh * 64 + tb0 + tbl) * 4 + kc0 + kcl) * 512 + lane2 * 8 + e0;
        base[dst] = t16[t_l][c_l];
        base[dst + 1] = t16[t_l][c_l + 1];
      }
    } else {
      int db0 = dbase >> 4, jc0 = t0 >> 5;
      #pragma unroll
      for (int fb = 0; fb < 8; ++fb) {
        int dbl = fb >> 1, jcl = fb & 1;
        int c_l = dbl * 16 + (lane2 & 15);
        int t_l = jcl * 32 + ((lane2 >> 4) << 3) + e0;
        size_t dst = ((bh * 8 + db0 + dbl) * 32 + jc0 + jcl) * 512 + lane2 * 8 + e0;
        out2[dst] = t16[t_l][c_l];
        out2[dst + 1] = t16[t_l + 1][c_l];
      }
    }
  } else {  // MODE 3
    unsigned short (*t16)[66] = (unsigned short(*)[66])lds;
    int b = row0g >> 10, t0 = row0g & 1023;
    if (n0 < 256) {
      size_t bh = (size_t)b * NHEAD + (n0 >> 6);
      int tb0 = t0 >> 4;
      #pragma unroll
      for (int fb = 0; fb < 8; ++fb) {
        int tbl = fb >> 1, kcl = fb & 1;
        int t_l = tbl * 16 + (lane2 & 15);
        int c_l = kcl * 32 + ((lane2 >> 4) << 3) + e0;
        size_t dst = ((bh * 64 + tb0 + tbl) * 2 + kcl) * 512 + lane2 * 8 + e0;
        out0[dst] = t16[t_l][c_l];
        out0[dst + 1] = t16[t_l][c_l + 1];
      }
    } else {
      size_t bh = (size_t)b * NHEAD + ((n0 - 256) >> 6);
      int jc0 = t0 >> 5;
      #pragma unroll
      for (int fb = 0; fb < 8; ++fb) {
        int dbl = fb >> 1, jcl = fb & 1;
        int c_l = dbl * 16 + (lane2 & 15);
        int t_l = jcl * 32 + ((lane2 >> 4) << 3) + e0;
        size_t dst = ((bh * 4 + dbl) * 32 + jc0 + jcl) * 512 + lane2 * 8 + e0;
        out1[dst] = t16[t_l][c_l];
        out1[dst + 1] = t16[t_l + 1][c_l];
      }
    }
  }
}

// ---------------- attention v7 (layers 0-10, D=64); 2-plane state in/out ----------------
__global__ __launch_bounds__(512) void k_attn_v7(
    const unsigned short* __restrict__ q,      // fp16 frag [bh][tb 64][kc 2][512]
    const unsigned short* __restrict__ Hh,     // fp16 [b][t][64]
    const unsigned short* __restrict__ vT,     // fp16 frag [bh][db 4][jc 32][512]
    const float* __restrict__ head_mask,
    const unsigned short* __restrict__ HbfIn, unsigned short* __restrict__ HbfOut, size_t hbPl,
    const float* __restrict__ g, const float* __restrict__ bta) {
  extern __shared__ char sh[];
  int bid = blockIdx.x;
  int xcd = bid & 7, u = bid >> 3;
  int b = xcd * 2 + (u >> 4);
  int pidx = u & 15;
  int tid = threadIdx.x;
  int wid = tid >> 6, lane = tid & 63;
  int h = wid & 3, grp = wid >> 2;
  int lr = lane & 15, lg = lane >> 4;
  int i0t[2] = { pidx * 32, (31 - pidx) * 32 };
  int NSS = (33 - pidx) >> 1;

  const char* gK = (const char*)(Hh + (size_t)b * SEQ * 64);
  char* KB = sh;
  unsigned short* sw = (unsigned short*)(sh + 16384 + wid * 2560);

  const unsigned short* qh = q + (size_t)(b * NHEAD + h) * 65536;
  const unsigned short* vh = vT + (size_t)(b * NHEAD + h) * 65536;

  f16x8 qf[2][2][2];
  #pragma unroll
  for (int t = 0; t < 2; ++t)
    #pragma unroll
    for (int mf = 0; mf < 2; ++mf)
      #pragma unroll
      for (int kf = 0; kf < 2; ++kf)
        qf[t][mf][kf] = *reinterpret_cast<const f16x8*>(
            qh + ((((i0t[t] >> 4) + mf) * 2 + kf) << 9) + lane * 8);
  f32x4 oacc[2][2][4] = {};

  u32x4 sreg;
  auto SLOAD = [&](int ss) {
    sreg = *reinterpret_cast<const u32x4*>(gK + (size_t)ss * 8192 + tid * 16);
  };
  auto SWRITE = [&](int buf) {
    int row = tid >> 3, colb = (tid & 7) * 16;
    *reinterpret_cast<u32x4*>(KB + buf * 8192 + row * 128 + (colb ^ ((row & 7) << 4))) = sreg;
  };

  SLOAD(0); SWRITE(0);
  __syncthreads();

  for (int ss = 0; ss < NSS; ++ss) {
    int cur = ss & 1;
    bool more = (ss + 1 < NSS);
    if (more) SLOAD(ss + 1);
    int js = ss * 64 + grp * 32;
    if (js < i0t[1] + 32) {
      f16x8 vch[4];
      #pragma unroll
      for (int nf = 0; nf < 4; ++nf)
        vch[nf] = *reinterpret_cast<const f16x8*>(vh + ((nf * 32 + (js >> 5)) << 9) + lane * 8);
      f16x8 kfr[2][2];
      #pragma unroll
      for (int nf2 = 0; nf2 < 2; ++nf2)
        #pragma unroll
        for (int kf = 0; kf < 2; ++kf) {
          int row = grp * 32 + nf2 * 16 + lr;
          int colb = kf * 64 + lg * 16;
          kfr[nf2][kf] = *reinterpret_cast<const f16x8*>(
              KB + cur * 8192 + row * 128 + (colb ^ ((row & 7) << 4)));
        }
      #pragma unroll
      for (int t = 0; t < 2; ++t) {
        if (js < i0t[t] + 32) {
          #pragma unroll
          for (int nf2 = 0; nf2 < 2; ++nf2) {
            #pragma unroll
            for (int mf = 0; mf < 2; ++mf) {
              f32x4 sacc = {};
              #pragma unroll
              for (int kf = 0; kf < 2; ++kf)
                sacc = __builtin_amdgcn_mfma_f32_16x16x32_f16(qf[t][mf][kf], kfr[nf2][kf], sacc, 0, 0, 0);
              #pragma unroll
              for (int r = 0; r < 4; ++r) {
                int i = i0t[t] + mf * 16 + lg * 4 + r;
                int j = js + nf2 * 16 + lr;
                float v = (j <= i) ? fmaxf(sacc[r], 0.f) : 0.f;
                sw[(mf * 16 + lg * 4 + r) * 40 + nf2 * 16 + lr] = f2h(v);
              }
            }
          }
          asm volatile("s_waitcnt lgkmcnt(0)" ::: "memory");
          __builtin_amdgcn_sched_barrier(0);
          #pragma unroll
          for (int mf = 0; mf < 2; ++mf) {
            f16x8 sf = *reinterpret_cast<const f16x8*>(&sw[(mf * 16 + lr) * 40 + lg * 8]);
            #pragma unroll
            for (int nf = 0; nf < 4; ++nf)
              oacc[t][mf][nf] = __builtin_amdgcn_mfma_f32_16x16x32_f16(sf, vch[nf], oacc[t][mf][nf], 0, 0, 0);
          }
        }
      }
    }
    if (more) SWRITE(cur ^ 1);
    __syncthreads();
  }

  float hm = head_mask[h];
  float hm3 = hm * hm * hm;
  float* f8 = (float*)sh;
  for (int t = 0; t < 2; ++t) {
    #pragma unroll
    for (int mf = 0; mf < 2; ++mf)
      #pragma unroll
      for (int nf = 0; nf < 4; ++nf)
        #pragma unroll
        for (int r = 0; r < 4; ++r)
          f8[wid * 2048 + (mf * 16 + lg * 4 + r) * 64 + nf * 16 + lr] = oacc[t][mf][nf][r] * hm3;
    __syncthreads();
    for (int idx = tid; idx < 8192; idx += 512) f8[idx] += f8[idx + 8192];
    __syncthreads();
    for (int idx = tid; idx < 4096; idx += 512) f8[idx] += f8[idx + 4096];
    __syncthreads();
    for (int idx = tid; idx < 2048; idx += 512) {
      int rr = idx >> 6;
      f8[idx] = (f8[idx] + f8[idx + 2048]) / (float)(i0t[t] + rr + 1);
    }
    __syncthreads();
    for (int rl = 0; rl < 4; ++rl) {
      int rr = wid * 4 + rl;
      size_t row = ((size_t)b * SEQ + i0t[t] + rr) * EMB;
      int c0 = lane, c1 = lane + 64;
      float x0 = b2f(HbfIn[row + c0]) + b2f(HbfIn[hbPl + row + c0]);
      float x1 = b2f(HbfIn[row + c1]) + b2f(HbfIn[hbPl + row + c1]) + f8[rr * 64 + lane];
      float s1 = x0 + x1, s2 = x0 * x0 + x1 * x1;
      #pragma unroll
      for (int off = 1; off < 64; off <<= 1) {
        s1 += __shfl_xor(s1, off);
        s2 += __shfl_xor(s2, off);
      }
      float mu = s1 * (1.f / 128.f);
      float var = s2 * (1.f / 128.f) - mu * mu;
      float rs = rsqrt_acc(var + LN_EPS);
      float y0 = (x0 - mu) * rs * g[c0] + bta[c0];
      float y1 = (x1 - mu) * rs * g[c1] + bta[c1];
      unsigned short h0, l0, h1, l1; split2(y0, h0, l0); split2(y1, h1, l1);
      HbfOut[row + c0] = h0; HbfOut[hbPl + row + c0] = l0;
      HbfOut[row + c1] = h1; HbfOut[hbPl + row + c1] = l1;
    }
    __syncthreads();
  }
}

// ---------------- fused attention (+LN1), last layer (DHEAD=128); 2-plane state ----------------
__global__ __launch_bounds__(512) void k_attn_fused(
    const unsigned short* __restrict__ q,      // fp16 frag [bh][tb 64][kc 4][512]
    const unsigned short* __restrict__ kbuf,   // fp16 frag [bh][tb 64][kc 4][512]
    const unsigned short* __restrict__ vT,     // fp16 frag [bh][db 8][jc 32][512]
    const float* __restrict__ head_mask,
    const unsigned short* __restrict__ HbfIn, unsigned short* __restrict__ HbfOut, size_t hbPl,
    const float* __restrict__ g, const float* __restrict__ bta) {
  constexpr int KF = 4, NFO = 8;
  constexpr int NT = SEQ / 32;
  extern __shared__ char sh[];      // attn: sw [0,20480); epilogue f8 [0,65536)
  int bid = blockIdx.x;
  int xcd = bid & 7, u = bid >> 3;
  int b = xcd * 2 + (u >> 4);
  int pidx = u & 15;
  int tid = threadIdx.x;
  int wid = tid >> 6, lane = tid & 63;
  int h = wid & 3, grp = wid >> 2;
  int lr = lane & 15, lg = lane >> 4;
  unsigned short* sw = (unsigned short*)(sh + wid * 2560);
  const unsigned short* qh = q + (size_t)(b * NHEAD + h) * 131072;
  const unsigned short* kh = kbuf + (size_t)(b * NHEAD + h) * 131072;
  const unsigned short* vh = vT + (size_t)(b * NHEAD + h) * 131072;
  float hm = head_mask[h];
  float hm3 = hm * hm * hm;

  for (int s = 0; s < 2; ++s) {
    int tile = (s == 0) ? pidx : (NT - 1 - pidx);
    int i0 = tile * 32;
    f16x8 qf[2][KF];
    #pragma unroll
    for (int mf = 0; mf < 2; ++mf)
      #pragma unroll
      for (int kf = 0; kf < KF; ++kf)
        qf[mf][kf] = *reinterpret_cast<const f16x8*>(
            qh + ((((i0 >> 4) + mf) * 4 + kf) << 9) + lane * 8);
    f32x4 oacc[2][NFO] = {};
    int jend = i0 + 32;
    for (int j0 = grp * 32; j0 < jend; j0 += 64) {
      f16x8 vch[NFO];
      #pragma unroll
      for (int nf = 0; nf < NFO; ++nf)
        vch[nf] = *reinterpret_cast<const f16x8*>(vh + ((nf * 32 + (j0 >> 5)) << 9) + lane * 8);
      #pragma unroll
      for (int nf2 = 0; nf2 < 2; ++nf2) {
        f16x8 kfr[KF];
        #pragma unroll
        for (int kf = 0; kf < KF; ++kf)
          kfr[kf] = *reinterpret_cast<const f16x8*>(
              kh + ((((j0 >> 4) + nf2) * 4 + kf) << 9) + lane * 8);
        #pragma unroll
        for (int mf = 0; mf < 2; ++mf) {
          f32x4 sacc = {};
          #pragma unroll
          for (int kf = 0; kf < KF; ++kf)
            sacc = __builtin_amdgcn_mfma_f32_16x16x32_f16(qf[mf][kf], kfr[kf], sacc, 0, 0, 0);
          #pragma unroll
          for (int r = 0; r < 4; ++r) {
            int i = i0 + mf * 16 + lg * 4 + r;
            int j = j0 + nf2 * 16 + lr;
            float v = (j <= i) ? fmaxf(sacc[r], 0.f) : 0.f;
            sw[(mf * 16 + lg * 4 + r) * 40 + nf2 * 16 + lr] = f2h(v);
          }
        }
      }
      asm volatile("s_waitcnt lgkmcnt(0)" ::: "memory");
      __builtin_amdgcn_sched_barrier(0);
      #pragma unroll
      for (int mf = 0; mf < 2; ++mf) {
        f16x8 sf = *reinterpret_cast<const f16x8*>(&sw[(mf * 16 + lr) * 40 + lg * 8]);
        #pragma unroll
        for (int nf = 0; nf < NFO; ++nf)
          oacc[mf][nf] = __builtin_amdgcn_mfma_f32_16x16x32_f16(sf, vch[nf], oacc[mf][nf], 0, 0, 0);
      }
    }
    // ---- parallel tree head-sum: f8[4 head-regions][32][128] ----
    float* f8 = (float*)sh;
    __syncthreads();
    if (wid < 4) {
      #pragma unroll
      for (int mf = 0; mf < 2; ++mf)
        #pragma unroll
        for (int nf = 0; nf < NFO; ++nf)
          #pragma unroll
          for (int r = 0; r < 4; ++r)
            f8[(wid & 3) * 4096 + (mf * 16 + lg * 4 + r) * 128 + nf * 16 + lr] = oacc[mf][nf][r] * hm3;
    }
    __syncthreads();
    if (wid >= 4) {
      #pragma unroll
      for (int mf = 0; mf < 2; ++mf)
        #pragma unroll
        for (int nf = 0; nf < NFO; ++nf)
          #pragma unroll
          for (int r = 0; r < 4; ++r)
            f8[(wid & 3) * 4096 + (mf * 16 + lg * 4 + r) * 128 + nf * 16 + lr] += oacc[mf][nf][r] * hm3;
    }
    __syncthreads();
    for (int idx = tid; idx < 8192; idx += 512) f8[idx] += f8[idx + 8192];
    __syncthreads();
    for (int idx = tid; idx < 4096; idx += 512) {
      int rr = idx >> 7;
      f8[idx] = (f8[idx] + f8[idx + 4096]) / (float)(i0 + rr + 1);
    }
    __syncthreads();
    for (int rl = 0; rl < 4; ++rl) {
      int rr = wid * 4 + rl;
      size_t row = ((size_t)b * SEQ + i0 + rr) * EMB;
      int c0 = lane, c1 = lane + 64;
      float x0 = b2f(HbfIn[row + c0]) + b2f(HbfIn[hbPl + row + c0]) + f8[rr * 128 + c0];
      float x1 = b2f(HbfIn[row + c1]) + b2f(HbfIn[hbPl + row + c1]) + f8[rr * 128 + c1];
      float s1 = x0 + x1, s2 = x0 * x0 + x1 * x1;
      #pragma unroll
      for (int off = 1; off < 64; off <<= 1) {
        s1 += __shfl_xor(s1, off);
        s2 += __shfl_xor(s2, off);
      }
      float mu = s1 * (1.f / 128.f);
      float var = s2 * (1.f / 128.f) - mu * mu;
      float rs = rsqrt_acc(var + LN_EPS);
      float y0 = (x0 - mu) * rs * g[c0] + bta[c0];
      float y1 = (x1 - mu) * rs * g[c1] + bta[c1];
      unsigned short h0, l0, h1, l1; split2(y0, h0, l0); split2(y1, h1, l1);
      HbfOut[row + c0] = h0; HbfOut[hbPl + row + c0] = l0;
      HbfOut[row + c1] = h1; HbfOut[hbPl + row + c1] = l1;
    }
    __syncthreads();
  }
}

// ---------------- fused MLP (mlp1+mlp2+residual+LN2), occupancy/ILP-tuned ----------------
// 16 rows/block, grid 1024, 4 waves. LDS = 40960 B exactly (4 blocks/CU):
//   As: 2 planes x [16][128] u16, XOR-swizzled (col ^ (row&7)<<3)    -> 8192 B
//   Mid: 2 planes x [16 kc][512] u16, fragment-ordered (linear reads) -> 32768 B
//   yb: f32[16][132] aliases Mid after mlp2 completes (extra barrier)
// W1/W2 fragments explicitly double-buffered (2-deep prefetch).
template<bool LAST>
__global__ __launch_bounds__(256) void k_mlpf(
    const unsigned short* __restrict__ A, size_t aPl,      // Hbf2 2-plane (post-LN1 y)
    const unsigned short* __restrict__ W1, size_t w1Pl, const float* __restrict__ b1,
    const unsigned short* __restrict__ W2, size_t w2Pl, const float* __restrict__ b2,
    unsigned short* __restrict__ HbfOut, size_t hbPl,
    unsigned short* __restrict__ Hh, float* __restrict__ Hst,
    const float* __restrict__ g, const float* __restrict__ bta) {
  extern __shared__ unsigned short mlds[];
  unsigned short* As = mlds;              // 4096 u16
  unsigned short* Mid = mlds + 4096;      // 16384 u16
  float* yb = (float*)Mid;                // aliases Mid (8448 B of 32768)
  int tid = threadIdx.x;
  int wid = tid >> 6, lane = tid & 63;
  int lr = lane & 15, lg = lane >> 4;
  int row0g = blockIdx.x * 16;
  {
    const unsigned short* gA = A + (size_t)row0g * 128;
    int row = tid >> 4;
    int sc = ((tid & 15) * 8) ^ ((row & 7) << 3);
    *reinterpret_cast<bf16x8*>(As + row * 128 + sc) =
        *reinterpret_cast<const bf16x8*>(gA + tid * 8);
    *reinterpret_cast<bf16x8*>(As + 2048 + row * 128 + sc) =
        *reinterpret_cast<const bf16x8*>(gA + aPl + tid * 8);
  }
  __syncthreads();
  bf16x8 afh[4], afl[4];
  #pragma unroll
  for (int kf = 0; kf < 4; ++kf) {
    int o = lr * 128 + ((kf * 32 + lg * 8) ^ ((lr & 7) << 3));
    afh[kf] = *reinterpret_cast<const bf16x8*>(As + o);
    afl[kf] = *reinterpret_cast<const bf16x8*>(As + 2048 + o);
  }
  // ---- mlp1: wave does n-tiles wid*8..+7; 2-deep W1 prefetch ----
  bf16x8 cwh[4], cwl[4], nwh[4], nwl[4];
  #pragma unroll
  for (int kf = 0; kf < 4; ++kf) {
    size_t bo = ((size_t)kf * 32 + wid * 8) * 512 + lane * 8;
    cwh[kf] = *reinterpret_cast<const bf16x8*>(W1 + bo);
    cwl[kf] = *reinterpret_cast<const bf16x8*>(W1 + w1Pl + bo);
  }
  #pragma unroll
  for (int j = 0; j < 8; ++j) {
    int ntile = wid * 8 + j;
    if (j < 7) {
      #pragma unroll
      for (int kf = 0; kf < 4; ++kf) {
        size_t bo = ((size_t)kf * 32 + ntile + 1) * 512 + lane * 8;
        nwh[kf] = *reinterpret_cast<const bf16x8*>(W1 + bo);
        nwl[kf] = *reinterpret_cast<const bf16x8*>(W1 + w1Pl + bo);
      }
    }
    f32x4 acc = {};
    #pragma unroll
    for (int kf = 0; kf < 4; ++kf) {
      acc = __builtin_amdgcn_mfma_f32_16x16x32_bf16(afh[kf], cwh[kf], acc, 0, 0, 0);
      acc = __builtin_amdgcn_mfma_f32_16x16x32_bf16(afl[kf], cwh[kf], acc, 0, 0, 0);
      acc = __builtin_amdgcn_mfma_f32_16x16x32_bf16(afh[kf], cwl[kf], acc, 0, 0, 0);
    }
    int c = ntile * 16 + lr;
    float bv = b1[c];
    int kc = c >> 5, sub = ((c & 31) >> 3) * 128 + (c & 7);
    #pragma unroll
    for (int r = 0; r < 4; ++r) {
      float v = fmaxf(acc[r] + bv, 0.f);
      unsigned short hi, lo; split2(v, hi, lo);
      int ma = kc * 512 + sub + (lg * 4 + r) * 8;
      Mid[ma] = hi;
      Mid[8192 + ma] = lo;
    }
    if (j < 7) {
      #pragma unroll
      for (int kf = 0; kf < 4; ++kf) { cwh[kf] = nwh[kf]; cwl[kf] = nwl[kf]; }
    }
  }
  __syncthreads();
  // ---- mlp2: wave does n-tiles wid*2, wid*2+1; 2-deep W2 prefetch; Mid reads linear ----
  f32x4 acc2[2] = {};
  bf16x8 c2h[2], c2l[2], n2h[2], n2l[2];
  #pragma unroll
  for (int j = 0; j < 2; ++j) {
    size_t bo = (size_t)(wid * 2 + j) * 512 + lane * 8;
    c2h[j] = *reinterpret_cast<const bf16x8*>(W2 + bo);
    c2l[j] = *reinterpret_cast<const bf16x8*>(W2 + w2Pl + bo);
  }
  #pragma unroll
  for (int kc = 0; kc < 16; ++kc) {
    if (kc < 15) {
      #pragma unroll
      for (int j = 0; j < 2; ++j) {
        size_t bo = ((size_t)(kc + 1) * 8 + wid * 2 + j) * 512 + lane * 8;
        n2h[j] = *reinterpret_cast<const bf16x8*>(W2 + bo);
        n2l[j] = *reinterpret_cast<const bf16x8*>(W2 + w2Pl + bo);
      }
    }
    int o = kc * 512 + lane * 8;
    bf16x8 amh = *reinterpret_cast<const bf16x8*>(Mid + o);
    bf16x8 aml = *reinterpret_cast<const bf16x8*>(Mid + 8192 + o);
    #pragma unroll
    for (int j = 0; j < 2; ++j) {
      acc2[j] = __builtin_amdgcn_mfma_f32_16x16x32_bf16(amh, c2h[j], acc2[j], 0, 0, 0);
      acc2[j] = __builtin_amdgcn_mfma_f32_16x16x32_bf16(aml, c2h[j], acc2[j], 0, 0, 0);
      acc2[j] = __builtin_amdgcn_mfma_f32_16x16x32_bf16(amh, c2l[j], acc2[j], 0, 0, 0);
    }
    if (kc < 15) {
      c2h[0] = n2h[0]; c2h[1] = n2h[1];
      c2l[0] = n2l[0]; c2l[1] = n2l[1];
    }
  }
  __syncthreads();   // all waves done reading Mid (yb aliases it)
  // ---- residual (reconstructed from swizzled As) into yb ----
  #pragma unroll
  for (int j = 0; j < 2; ++j) {
    int c = (wid * 2 + j) * 16 + lr;
    float bv = b2[c];
    #pragma unroll
    for (int r = 0; r < 4; ++r) {
      int row = lg * 4 + r;
      int sc = c ^ ((row & 7) << 3);
      float yres = b2f(As[row * 128 + sc]) + b2f(As[2048 + row * 128 + sc]);
      yb[row * 132 + c] = acc2[j][r] + bv + yres;
    }
  }
  __syncthreads();
  // ---- LN2: wave owns rows wid*4 .. wid*4+3 ----
  for (int rl = 0; rl < 4; ++rl) {
    int row = wid * 4 + rl;
    size_t gro = (size_t)(row0g + row) * EMB;
    int c0 = lane, c1 = lane + 64;
    float x0 = yb[row * 132 + c0];
    float x1 = yb[row * 132 + c1];
    float s1 = x0 + x1, s2 = x0 * x0 + x1 * x1;
    #pragma unroll
    for (int off = 1; off < 64; off <<= 1) {
      s1 += __shfl_xor(s1, off);
      s2 += __shfl_xor(s2, off);
    }
    float mu = s1 * (1.f / 128.f);
    float var = s2 * (1.f / 128.f) - mu * mu;
    float rs = rsqrt_acc(var + LN_EPS);
    float y0 = (x0 - mu) * rs * g[c0] + bta[c0];
    float y1 = (x1 - mu) * rs * g[c1] + bta[c1];
    unsigned short h0, l0, h1, l1; split2(y0, h0, l0); split2(y1, h1, l1);
    HbfOut[gro + c0] = h0; HbfOut[hbPl + gro + c0] = l0;
    HbfOut[gro + c1] = h1; HbfOut[hbPl + gro + c1] = l1;
    Hh[(size_t)(row0g + row) * 64 + lane] = f2h(y0);
    if (LAST) { Hst[gro + c0] = y0; Hst[gro + c1] = y1; }
  }
}

// ---------------- readout ----------------
__global__ __launch_bounds__(64) void k_readout(const float* __restrict__ H,
                                                const float* __restrict__ W, const float* __restrict__ b0,
                                                float* __restrict__ out) {
  int idx = blockIdx.x;           // b*512 + p
  int b = idx >> 9, p = idx & 511;
  size_t row = ((size_t)b * SEQ + 2 * p) * EMB;
  int lane = threadIdx.x;
  float acc = H[row + lane] * W[lane] + H[row + 64 + lane] * W[64 + lane];
  #pragma unroll
  for (int off = 1; off < 64; off <<= 1) acc += __shfl_xor(acc, off);
  if (lane == 0) out[idx] = acc + b0[0];
}

extern "C" void kernel_launch(void* const* d_in, const int* in_sizes, int n_in,
                              void* d_out, int out_size, void* d_ws, size_t ws_size,
                              hipStream_t stream) {
  (void)in_sizes; (void)n_in; (void)out_size; (void)ws_size;
  const float* xs        = (const float*)d_in[0];
  const float* ys        = (const float*)d_in[1];
  const float* head_mask = (const float*)d_in[2];
  const float* read_in_W = (const float*)d_in[3];
  const float* read_in_b = (const float*)d_in[4];
  const float* qW        = (const float*)d_in[5];
  const float* vW        = (const float*)d_in[6];
  const float* qW_last   = (const float*)d_in[7];
  const float* kW_last   = (const float*)d_in[8];
  const float* vW_last   = (const float*)d_in[9];
  const float* ln1_g     = (const float*)d_in[10];
  const float* ln1_b     = (const float*)d_in[11];
  const float* ln2_g     = (const float*)d_in[12];
  const float* ln2_b     = (const float*)d_in[13];
  const float* mlp_W1    = (const float*)d_in[14];
  const float* mlp_b1    = (const float*)d_in[15];
  const float* mlp_W2    = (const float*)d_in[16];
  const float* mlp_b2    = (const float*)d_in[17];
  const float* ro_W      = (const float*)d_in[18];
  const float* ro_b      = (const float*)d_in[19];

  const size_t HPL   = (size_t)BS * SEQ * EMB;          // 2M
  const size_t QVWPL = (size_t)11 * 512 * 128;
  const size_t W1PL  = (size_t)12 * 512 * 128;
  const size_t W2PL  = (size_t)12 * 512 * 128;
  const size_t LASTPL= (size_t)1536 * 128;
  const size_t VOFF  = (size_t)BS * NHEAD * 65536;      // v region inside qbuf

  char* ws = (char*)d_ws;
  size_t off = 0;
  auto alloc = [&](size_t bytes) -> void* {
    void* p = ws + off;
    off += (bytes + 255) & ~(size_t)255;
    return p;
  };
  float* H             = (float*)alloc(HPL * 4);                  // 8 MB (final layer only)
  unsigned short* Hbf  = (unsigned short*)alloc(2 * HPL * 2);     // 8 MB (state)
  unsigned short* Hbf2 = (unsigned short*)alloc(2 * HPL * 2);     // 8 MB (post-LN1)
  unsigned short* Hh   = (unsigned short*)alloc((size_t)BS * SEQ * 64 * 2);  // 2 MB
  unsigned short* qbuf = (unsigned short*)alloc((size_t)BS * NHEAD * 131072 * 2); // q | v (v7) / q-last
  unsigned short* kmid = (unsigned short*)alloc((size_t)BS * NHEAD * 131072 * 2); // k-last frag
  unsigned short* vTl  = (unsigned short*)alloc((size_t)BS * NHEAD * 131072 * 2); // last v frag
  unsigned short* qvWT = (unsigned short*)alloc(2 * QVWPL * 2);
  unsigned short* W1T  = (unsigned short*)alloc(2 * W1PL * 2);
  unsigned short* W2T  = (unsigned short*)alloc(2 * W2PL * 2);
  unsigned short* lastT= (unsigned short*)alloc(2 * LASTPL * 2);

  { int tot = 11 * 512 * 128; k_prep_qvfrag<<<dim3((tot + 255) / 256), 256, 0, stream>>>(qW, vW, qvWT, QVWPL); }
  { int tot = 12 * 512 * 128; k_prep_fragT<<<dim3((tot + 255) / 256), 256, 0, stream>>>(mlp_W1, W1T, W1PL, 12, 128, 512, 512, 128); }
  { int tot = 12 * 512 * 128; k_prep_fragT<<<dim3((tot + 255) / 256), 256, 0, stream>>>(mlp_W2, W2T, W2PL, 12, 512, 128, 128, 512); }
  { int tot = 1536 * 128; k_prep_lastfrag<<<dim3((tot + 255) / 256), 256, 0, stream>>>(qW_last, kW_last, vW_last, lastT, LASTPL); }

  k_combine_readin<<<dim3(BS * SEQ), 128, 0, stream>>>(xs, ys, read_in_W, read_in_b, Hbf, HPL, Hh);

  const int GEMM_LDS = 2 * 64 * 136 * 2;     // 34816 B
  const int MLPF_LDS = (4096 + 16384) * 2;   // 40960 B -> 4 blocks/CU, single batch

  for (int l = 0; l < 11; ++l) {
    k_gemm<3, false><<<dim3(256, 8), 256, GEMM_LDS, stream>>>(
        Hbf, HPL, qvWT + (size_t)l * 65536, QVWPL, nullptr, 512,
        qbuf, qbuf + VOFF, nullptr);
    k_attn_v7<<<dim3(256), 512, 65536, stream>>>(
        qbuf, Hh, qbuf + VOFF, head_mask, Hbf, Hbf2, HPL, ln1_g + l * 128, ln1_b + l * 128);
    k_mlpf<false><<<dim3(1024), 256, MLPF_LDS, stream>>>(
        Hbf2, HPL, W1T + (size_t)l * 65536, W1PL, mlp_b1 + l * 512,
        W2T + (size_t)l * 65536, W2PL, mlp_b2 + l * 128,
        Hbf, HPL, Hh, nullptr, ln2_g + l * 128, ln2_b + l * 128);
  }
  // last layer
  k_gemm<2, false><<<dim3(256, 24), 256, GEMM_LDS, stream>>>(
      Hbf, HPL, lastT, LASTPL, nullptr, 1536, qbuf, kmid, vTl);
  k_attn_fused<<<dim3(256), 512, 65536, stream>>>(
      qbuf, kmid, vTl, head_mask, Hbf, Hbf2, HPL, ln1_g + 11 * 128, ln1_b + 11 * 128);
  k_mlpf<true><<<dim3(1024), 256, MLPF_LDS, stream>>>(
      Hbf2, HPL, W1T + (size_t)11 * 65536, W1PL, mlp_b1 + 11 * 512,
      W2T + (size_t)11 * 65536, W2PL, mlp_b2 + 11 * 128,
      Hbf, HPL, Hh, H, ln2_g + 11 * 128, ln2_b + 11 * 128);

  k_readout<<<dim3(8192), 64, 0, stream>>>(H, ro_W, ro_b, (float*)d_out);
}